// Round 13
// baseline (104.362 us; speedup 1.0000x reference)
//
#include <hip/hip_runtime.h>

// ---------------------------------------------------------------------------
// Attention_43868795961547: LN -> QKV -> MHA(1025 keys) -> proj
// b=8, n=1024, dim=512, heads=8, dh=64. bf16 MFMA, f32 accum.
// Round 13: k_qkv -> 256x256 tile, BK=64, 8 waves, 2-buffer LDS (128KB),
// XOR-swizzled rows (chunk ^= row&7, both-sides involution), counted
// vmcnt(8), 2 barriers per 64-wide K-step (8 steps). m230: this structure
// = 682 TF refcheck'd. k_pre/k_attn/k_out identical to round 12 (passing).
// ---------------------------------------------------------------------------

typedef __attribute__((ext_vector_type(4))) float f32x4;
typedef __attribute__((ext_vector_type(16))) float f32x16;
typedef __attribute__((ext_vector_type(8))) short bf16x8;
typedef __attribute__((ext_vector_type(8))) unsigned short u16x8;

#define MFMA16(a, b, c) __builtin_amdgcn_mfma_f32_16x16x32_bf16(a, b, c, 0, 0, 0)
#define MFMA32(a, b, c) __builtin_amdgcn_mfma_f32_32x32x16_bf16(a, b, c, 0, 0, 0)

#define GLD16(gsrc, ldst)                                                     \
  __builtin_amdgcn_global_load_lds(                                           \
      (const __attribute__((address_space(1))) void*)(gsrc),                  \
      (__attribute__((address_space(3))) void*)(ldst), 16, 0, 0)

#define KPAD 1088   // keys padded: 17 tiles of 64

// Q pre-scale: dots*0.125 in exp2-domain => fold 0.125*log2(e) into Q.
#define QSCALE 0.18033688011112042f

__device__ __forceinline__ unsigned short f2bf(float f) {
  union { float f; unsigned int u; } c; c.f = f;
  unsigned int u = c.u;
  u += 0x7fffu + ((u >> 16) & 1u);   // RNE
  return (unsigned short)(u >> 16);
}

__device__ __forceinline__ unsigned int cvtpk_bf16(float lo, float hi) {
  unsigned int r;
  asm("v_cvt_pk_bf16_f32 %0, %1, %2" : "=v"(r) : "v"(lo), "v"(hi));
  return r;
}

// ---- kernel 1: fused pre-pass --------------------------------------------
__global__ __launch_bounds__(256) void k_pre(const float* __restrict__ img,
                                             const float* __restrict__ tab,
                                             const float* __restrict__ w_qkv,
                                             const float* __restrict__ w_tab,
                                             const float* __restrict__ w_out,
                                             const float* __restrict__ ln_w,
                                             const float* __restrict__ ln_b,
                                             unsigned short* __restrict__ x_bf,
                                             unsigned short* __restrict__ wqt,
                                             unsigned short* __restrict__ wot,
                                             unsigned short* __restrict__ kh,
                                             unsigned short* __restrict__ vt) {
  int blk = blockIdx.x, tid = threadIdx.x;
  if (blk < 256) {
    __shared__ unsigned short tbuf[64][68];
    const float* src;
    unsigned short* dst;
    int k0, n0, ldin;
    if (blk < 192) {
      int ti = blk / 24, tj = blk % 24;
      k0 = ti * 64; n0 = tj * 64; ldin = 1536;
      src = w_qkv; dst = wqt;
    } else {
      int g = blk - 192;
      int ti = g >> 3, tj = g & 7;
      k0 = ti * 64; n0 = tj * 64; ldin = 512;
      src = w_out; dst = wot;
    }
    int rr = tid >> 4, c4 = (tid & 15) * 4;
    #pragma unroll
    for (int i = 0; i < 4; ++i) {
      int r = i * 16 + rr;
      float4 v = *(const float4*)(src + (size_t)(k0 + r) * ldin + n0 + c4);
      tbuf[c4 + 0][r] = f2bf(v.x);
      tbuf[c4 + 1][r] = f2bf(v.y);
      tbuf[c4 + 2][r] = f2bf(v.z);
      tbuf[c4 + 3][r] = f2bf(v.w);
    }
    __syncthreads();
    #pragma unroll
    for (int i = 0; i < 4; ++i) {
      int r = i * 16 + rr;
      ushort4 w = *(const ushort4*)&tbuf[r][c4];
      *(ushort4*)(dst + (size_t)(n0 + r) * 512 + k0 + c4) = w;
    }
  } else if (blk < 2304) {
    int wid = tid >> 6, lane = tid & 63;
    int row = (blk - 256) * 4 + wid;
    const float* src = img + (size_t)row * 512;
    float4 v0 = *(const float4*)(src + lane * 8);
    float4 v1 = *(const float4*)(src + lane * 8 + 4);
    float x[8] = {v0.x, v0.y, v0.z, v0.w, v1.x, v1.y, v1.z, v1.w};
    float s = 0.f, sq = 0.f;
    #pragma unroll
    for (int j = 0; j < 8; ++j) { s += x[j]; sq += x[j] * x[j]; }
    #pragma unroll
    for (int off = 32; off >= 1; off >>= 1) {
      s  += __shfl_xor(s, off);
      sq += __shfl_xor(sq, off);
    }
    float mean = s * (1.0f / 512.0f);
    float var  = sq * (1.0f / 512.0f) - mean * mean;
    float rs = rsqrtf(var + 1e-5f);
    float4 w0 = *(const float4*)(ln_w + lane * 8);
    float4 w1 = *(const float4*)(ln_w + lane * 8 + 4);
    float4 b0 = *(const float4*)(ln_b + lane * 8);
    float4 b1 = *(const float4*)(ln_b + lane * 8 + 4);
    float w[8] = {w0.x, w0.y, w0.z, w0.w, w1.x, w1.y, w1.z, w1.w};
    float bb[8] = {b0.x, b0.y, b0.z, b0.w, b1.x, b1.y, b1.z, b1.w};
    bf16x8 o;
    #pragma unroll
    for (int j = 0; j < 8; ++j)
      o[j] = (short)f2bf((x[j] - mean) * rs * w[j] + bb[j]);
    *(bf16x8*)(x_bf + (size_t)row * 512 + lane * 8) = o;
  } else {
    __shared__ float tl[512];
    __shared__ float red[4][64];
    __shared__ float ws_[4], wq_[4];
    int blk2 = blk - 2304;           // 128 blocks
    int b = blk2 >> 4, chunk = blk2 & 15;
    int t = tid;
    int lane = t & 63, wid = t >> 6;
    int cl = t & 63;
    int ks = t >> 6;
    int col = chunk * 64 + cl;

    {
      int h = chunk & 7;
      int bh = b * 8 + h;
      u16x8 z = (u16x8)(0);
      if (chunk < 8) {
        unsigned short* base = kh + ((size_t)bh * KPAD + 1024) * 64;
        #pragma unroll
        for (int i = 0; i < 2; ++i)
          *(u16x8*)(base + (t + i * 256) * 8) = z;
      } else {
        #pragma unroll
        for (int i = 0; i < 2; ++i) {
          int idx = t + i * 256;
          int d = idx >> 3, ch = idx & 7;
          *(u16x8*)(vt + ((size_t)bh * 64 + d) * KPAD + 1024 + ch * 8) = z;
        }
      }
    }

    float2 tv = *(const float2*)(tab + (size_t)b * 512 + t * 2);
    float s_ = tv.x + tv.y, q_ = tv.x * tv.x + tv.y * tv.y;
    #pragma unroll
    for (int off = 32; off >= 1; off >>= 1) {
      s_ += __shfl_xor(s_, off);
      q_ += __shfl_xor(q_, off);
    }
    if (lane == 0) { ws_[wid] = s_; wq_[wid] = q_; }
    __syncthreads();
    float S = ws_[0] + ws_[1] + ws_[2] + ws_[3];
    float Qq = wq_[0] + wq_[1] + wq_[2] + wq_[3];
    float mean = S * (1.0f / 512.0f);
    float var = Qq * (1.0f / 512.0f) - mean * mean;
    float rs = rsqrtf(var + 1e-5f);
    tl[t * 2 + 0] = (tv.x - mean) * rs * ln_w[t * 2 + 0] + ln_b[t * 2 + 0];
    tl[t * 2 + 1] = (tv.y - mean) * rs * ln_w[t * 2 + 1] + ln_b[t * 2 + 1];
    __syncthreads();

    const float* wp = w_tab + 512 + col + (size_t)(ks * 128) * 1536;
    float s = 0.f;
    #pragma unroll 8
    for (int k = 0; k < 128; ++k)
      s += tl[ks * 128 + k] * wp[(size_t)k * 1536];
    red[ks][cl] = s;
    __syncthreads();
    if (ks == 0) {
      float v = red[0][cl] + red[1][cl] + red[2][cl] + red[3][cl];
      int part = col >> 9, hd = col & 511, h = hd >> 6, d = hd & 63;
      int bh = b * 8 + h;
      unsigned short hv = f2bf(v);
      if (part == 0) kh[((size_t)bh * KPAD + 1024) * 64 + d] = hv;
      else           vt[((size_t)bh * 64 + d) * KPAD + 1024] = hv;
    }
  }
}

// ---- kernel 4: QKV GEMM, 256x256 tile, BK=64, XOR-swizzled LDS ------------
// 192 blocks (32 x 6), 512 thr / 8 waves (2M x 4N), wave tile 128x64.
// LDS 128KB: As/Bs[2][256*64]. Rows = 64 bf16 = 8 chunks of 16B; physical
// chunk q = logical c ^ (row&7); staged via pre-swizzled global source
// (linear LDS dest), read back with the same XOR (involution).
__global__ __launch_bounds__(512, 2) void k_qkv(const unsigned short* __restrict__ x_bf,
                                                const unsigned short* __restrict__ wqt,
                                                unsigned short* __restrict__ qh,
                                                unsigned short* __restrict__ kh,
                                                unsigned short* __restrict__ vt) {
  __shared__ unsigned short As[2][256 * 64];
  __shared__ unsigned short Bs[2][256 * 64];
  int tid = threadIdx.x;                    // 0..511
  int wid = tid >> 6, lane = tid & 63;
  int bm = blockIdx.x & 31, bn = blockIdx.x >> 5;   // 32 x 6
  int r0 = bm * 256, c0 = bn * 256;
  int lr = lane & 15, hc = lane >> 4;       // fragment row / k-chunk
  int wr = (wid >> 2) * 128, wc = (wid & 3) * 64;   // 2M x 4N wave grid

  // staging: 4 A-chunks + 4 B-chunks per thread per K-tile.
  // chunk id = i*512 + tid; row = id>>3, linear pos q = id&7,
  // logical k-chunk c = q ^ (row&7)  (pre-swizzled source).
  int srowA[4], scA[4];
  #pragma unroll
  for (int i = 0; i < 4; ++i) {
    int id = i * 512 + tid;
    srowA[i] = id >> 3;
    scA[i] = (id & 7) ^ (srowA[i] & 7);
  }

  f32x4 acc[8][4];
  #pragma unroll
  for (int mi = 0; mi < 8; ++mi)
    #pragma unroll
    for (int ni = 0; ni < 4; ++ni)
      acc[mi][ni] = (f32x4){0.f, 0.f, 0.f, 0.f};

  // stage K-tile kt into buffer buf (8 GLD16 per thread)
  #define STAGE_QKV(kt, buf)                                                   \
    do {                                                                       \
      int kb = (kt) * 64;                                                      \
      _Pragma("unroll")                                                        \
      for (int i = 0; i < 4; ++i)                                              \
        GLD16(x_bf + (size_t)(r0 + srowA[i]) * 512 + kb + scA[i] * 8,          \
              &As[buf][(i * 512 + tid) * 8]);                                  \
      _Pragma("unroll")                                                        \
      for (int i = 0; i < 4; ++i)                                              \
        GLD16(wqt + (size_t)(c0 + srowA[i]) * 512 + kb + scA[i] * 8,           \
              &Bs[buf][(i * 512 + tid) * 8]);                                  \
    } while (0)

  STAGE_QKV(0, 0);
  STAGE_QKV(1, 1);

  for (int t = 0; t < 8; ++t) {
    int cur = t & 1;
    if (t < 7) asm volatile("s_waitcnt vmcnt(8)" ::: "memory");
    else       asm volatile("s_waitcnt vmcnt(0)" ::: "memory");
    __builtin_amdgcn_s_barrier();           // tile t resident block-wide
    __builtin_amdgcn_sched_barrier(0);
    #pragma unroll
    for (int kk = 0; kk < 2; ++kk) {
      bf16x8 af[8], bfr[4];
      #pragma unroll
      for (int mi = 0; mi < 8; ++mi) {
        int row = wr + mi * 16 + lr;
        int q = (kk * 4 + hc) ^ (row & 7);
        af[mi] = *(const bf16x8*)&As[cur][row * 64 + q * 8];
      }
      #pragma unroll
      for (int ni = 0; ni < 4; ++ni) {
        int row = wc + ni * 16 + lr;
        int q = (kk * 4 + hc) ^ (row & 7);
        bfr[ni] = *(const bf16x8*)&Bs[cur][row * 64 + q * 8];
      }
      __builtin_amdgcn_s_setprio(1);
      #pragma unroll
      for (int mi = 0; mi < 8; ++mi)
        #pragma unroll
        for (int ni = 0; ni < 4; ++ni)
          acc[mi][ni] = MFMA16(af[mi], bfr[ni], acc[mi][ni]);
      __builtin_amdgcn_s_setprio(0);
    }
    __builtin_amdgcn_s_barrier();           // all waves done reading buf[cur]
    __builtin_amdgcn_sched_barrier(0);
    if (t < 6) STAGE_QKV(t + 2, cur);       // refill freed buffer
  }
  #undef STAGE_QKV

  #pragma unroll
  for (int ni = 0; ni < 4; ++ni) {
    int col0 = c0 + wc + ni * 16;
    int which = col0 >> 9;
    int hh = (col0 & 511) >> 6;
    int d = (col0 & 63) + lr;
    #pragma unroll
    for (int mi = 0; mi < 8; ++mi)
      #pragma unroll
      for (int reg = 0; reg < 4; ++reg) {
        int row = r0 + wr + mi * 16 + (lane >> 4) * 4 + reg;
        int b = row >> 10, n = row & 1023;
        int bh = b * 8 + hh;
        float v = acc[mi][ni][reg];
        if (which == 0) {
          qh[((size_t)bh * 1024 + n) * 64 + d] = f2bf(v * QSCALE);
        } else if (which == 1) {
          kh[((size_t)bh * KPAD + n) * 64 + d] = f2bf(v);
        } else {
          vt[((size_t)bh * 64 + d) * KPAD + n] = f2bf(v);
        }
      }
  }
}

// ---- kernel 5: flash attention, 8-wave block + LDS-staged K/V -------------
__global__ __launch_bounds__(512, 4) void k_attn(const unsigned short* __restrict__ qh,
                                                 const unsigned short* __restrict__ kh,
                                                 const unsigned short* __restrict__ vt,
                                                 unsigned short* __restrict__ ao) {
  __shared__ __align__(16) unsigned short Ks[2][4096];  // [64 key][64 d] swz
  __shared__ __align__(16) unsigned short Vs[2][4096];  // [64 d][64 key] swz
  int tid = threadIdx.x;
  int wid = tid >> 6, lane = tid & 63;
  int bid = blockIdx.x;
  int swz = ((bid & 7) << 5) | (bid >> 3);   // bijective; 8 bh per XCD
  int bh = swz >> 2;
  int q0 = (swz & 3) * 256 + wid * 32;
  int lq = lane & 31, half = lane >> 5;

  const unsigned short* Q  = qh + (size_t)bh * 1024 * 64;
  const unsigned short* Kg = kh + (size_t)bh * KPAD * 64;
  const unsigned short* Vg = vt + (size_t)bh * 64 * KPAD;

  int xr = tid >> 3;
  int xc = (tid & 7) ^ (xr & 7);
  const unsigned short* kg_src = Kg + xr * 64 + xc * 8;
  const unsigned short* vg_src = Vg + (size_t)xr * KPAD + xc * 8;
  unsigned short* kdstA = &Ks[0][wid * 512];
  unsigned short* kdstB = &Ks[1][wid * 512];
  unsigned short* vdstA = &Vs[0][wid * 512];
  unsigned short* vdstB = &Vs[1][wid * 512];

  bf16x8 qf[4];
  const unsigned short* qlane = Q + (size_t)(q0 + lq) * 64 + half * 8;
  #pragma unroll
  for (int dt = 0; dt < 4; ++dt)
    qf[dt] = *(const bf16x8*)(qlane + dt * 16);

  f32x16 o0 = (f32x16)(0.0f), o1 = (f32x16)(0.0f);
  float m = -1e30f, lsum = 0.f;

  GLD16(kg_src, kdstA);
  GLD16(vg_src, vdstA);
  __syncthreads();

  for (int kt = 0; kt < 17; ++kt) {
    int cur = kt & 1;
    if (kt < 16) {
      GLD16(kg_src + (kt + 1) * 4096, cur ? kdstA : kdstB);
      GLD16(vg_src + (kt + 1) * 64,   cur ? vdstA : vdstB);
    }
    const unsigned short* Kb = Ks[cur];
    const unsigned short* Vb = Vs[cur];
    #pragma unroll
    for (int sub = 0; sub < 2; ++sub) {
      int krow = sub * 32 + lq;
      bf16x8 kf[4];
      #pragma unroll
      for (int dt = 0; dt < 4; ++dt) {
        int ch = (half + dt * 2) ^ (krow & 7);
        kf[dt] = *(const bf16x8*)&Kb[krow * 64 + ch * 8];
      }
      f32x16 s = (f32x16)(0.0f);
      __builtin_amdgcn_s_setprio(1);
      #pragma unroll
      for (int dt = 0; dt < 4; ++dt)
        s = MFMA32(kf[dt], qf[dt], s);
      __builtin_amdgcn_s_setprio(0);
      if (kt == 16) {
        if (sub == 0) {
          #pragma unroll
          for (int reg = 0; reg < 16; ++reg) {
            if (reg == 0) { if (half) s[0] = -1e30f; }
            else s[reg] = -1e30f;
          }
        } else {
          #pragma unroll
          for (int reg = 0; reg < 16; ++reg) s[reg] = -1e30f;
        }
      }
      float pmax = s[0];
      #pragma unroll
      for (int reg = 1; reg < 16; ++reg) pmax = fmaxf(pmax, s[reg]);
      pmax = fmaxf(pmax, __shfl_xor(pmax, 32));
      if (!__all(pmax <= m + 8.0f)) {
        float mnew = fmaxf(m, pmax);
        float al = __builtin_amdgcn_exp2f(m - mnew);
        lsum *= al;
        #pragma unroll
        for (int reg = 0; reg < 16; ++reg) { o0[reg] *= al; o1[reg] *= al; }
        m = mnew;
      }
      float p[16];
      float ls = 0.f;
      #pragma unroll
      for (int reg = 0; reg < 16; ++reg) {
        p[reg] = __builtin_amdgcn_exp2f(s[reg] - m);
        ls += p[reg];
      }
      lsum += ls;
      unsigned int c0x0 = cvtpk_bf16(p[0],  p[1]);
      unsigned int c0x1 = cvtpk_bf16(p[2],  p[3]);
      unsigned int c0y0 = cvtpk_bf16(p[4],  p[5]);
      unsigned int c0y1 = cvtpk_bf16(p[6],  p[7]);
      unsigned int c1x0 = cvtpk_bf16(p[8],  p[9]);
      unsigned int c1x1 = cvtpk_bf16(p[10], p[11]);
      unsigned int c1y0 = cvtpk_bf16(p[12], p[13]);
      unsigned int c1y1 = cvtpk_bf16(p[14], p[15]);
      asm volatile("v_permlane32_swap_b32 %0, %1" : "+v"(c0x0), "+v"(c0y0));
      asm volatile("v_permlane32_swap_b32 %0, %1" : "+v"(c0x1), "+v"(c0y1));
      asm volatile("v_permlane32_swap_b32 %0, %1" : "+v"(c1x0), "+v"(c1y0));
      asm volatile("v_permlane32_swap_b32 %0, %1" : "+v"(c1x1), "+v"(c1y1));
      union { unsigned int w[4]; bf16x8 v; } f0, f1;
      f0.w[0] = c0x0; f0.w[1] = c0x1; f0.w[2] = c0y0; f0.w[3] = c0y1;
      f1.w[0] = c1x0; f1.w[1] = c1x1; f1.w[2] = c1y0; f1.w[3] = c1y1;
      int vr0 = lq, vr1 = lq + 32;
      int cb = sub * 4 + half;
      bf16x8 vf0 = *(const bf16x8*)&Vb[vr0 * 64 + ((cb + 0) ^ (vr0 & 7)) * 8];
      bf16x8 vf1 = *(const bf16x8*)&Vb[vr0 * 64 + ((cb + 2) ^ (vr0 & 7)) * 8];
      bf16x8 vf2 = *(const bf16x8*)&Vb[vr1 * 64 + ((cb + 0) ^ (vr1 & 7)) * 8];
      bf16x8 vf3 = *(const bf16x8*)&Vb[vr1 * 64 + ((cb + 2) ^ (vr1 & 7)) * 8];
      __builtin_amdgcn_s_setprio(1);
      o0 = MFMA32(vf0, f0.v, o0);
      o0 = MFMA32(vf1, f1.v, o0);
      o1 = MFMA32(vf2, f0.v, o1);
      o1 = MFMA32(vf3, f1.v, o1);
      __builtin_amdgcn_s_setprio(0);
    }
    __syncthreads();
  }
  lsum += __shfl_xor(lsum, 32);
  float rl = 1.0f / lsum;
  int b = bh >> 3, h = bh & 7;
  unsigned short* aorow = ao + ((size_t)(b * 1024 + q0 + lq)) * 512 + h * 64;
  #pragma unroll
  for (int dt2 = 0; dt2 < 2; ++dt2) {
    #pragma unroll
    for (int g = 0; g < 4; ++g) {
      ushort4 pk;
      float v0 = (dt2 ? o1[4 * g + 0] : o0[4 * g + 0]) * rl;
      float v1 = (dt2 ? o1[4 * g + 1] : o0[4 * g + 1]) * rl;
      float v2 = (dt2 ? o1[4 * g + 2] : o0[4 * g + 2]) * rl;
      float v3 = (dt2 ? o1[4 * g + 3] : o0[4 * g + 3]) * rl;
      pk.x = f2bf(v0); pk.y = f2bf(v1); pk.z = f2bf(v2); pk.w = f2bf(v3);
      *(ushort4*)(aorow + dt2 * 32 + 8 * g + 4 * half) = pk;
    }
  }
}

// ---- kernel 6: output GEMM + bias, 8 waves (64x32/wave) -------------------
__global__ __launch_bounds__(512, 6) void k_out(const unsigned short* __restrict__ ao,
                                                const unsigned short* __restrict__ wot,
                                                const float* __restrict__ b_out,
                                                float* __restrict__ out) {
  __shared__ unsigned short As[3][128 * 32];
  __shared__ unsigned short Bs[3][128 * 32];
  int tid = threadIdx.x;
  int wid = tid >> 6, lane = tid & 63;
  int bm = blockIdx.x & 63, bn = blockIdx.x >> 6;   // 64 x 4
  int r0 = bm * 128, c0 = bn * 128;
  int lr = lane & 15, lk = (lane >> 4) * 8;
  int wr = (wid >> 2) * 64, wc = (wid & 3) * 32;
  int srow = tid >> 2, scol = (tid & 3) * 8;
  const unsigned short* gA = ao  + (size_t)(r0 + srow) * 512 + scol;
  const unsigned short* gB = wot + (size_t)(c0 + srow) * 512 + scol;
  int ldsoff = tid * 8;

  f32x4 acc[4][2];
  #pragma unroll
  for (int mi = 0; mi < 4; ++mi)
    #pragma unroll
    for (int ni = 0; ni < 2; ++ni)
      acc[mi][ni] = (f32x4){0.f, 0.f, 0.f, 0.f};

  GLD16(gA,      &As[0][ldsoff]);
  GLD16(gB,      &Bs[0][ldsoff]);
  GLD16(gA + 32, &As[1][ldsoff]);
  GLD16(gB + 32, &Bs[1][ldsoff]);

  int cur = 0, pre = 2;
  for (int t = 0; t < 16; ++t) {
    if (t < 15) asm volatile("s_waitcnt vmcnt(2)" ::: "memory");
    else        asm volatile("s_waitcnt vmcnt(0)" ::: "memory");
    __builtin_amdgcn_s_barrier();
    if (t < 14) {
      int k2 = (t + 2) * 32;
      GLD16(gA + k2, &As[pre][ldsoff]);
      GLD16(gB + k2, &Bs[pre][ldsoff]);
    }
    bf16x8 af[4], bfr[2];
    #pragma unroll
    for (int mi = 0; mi < 4; ++mi)
      af[mi] = *(const bf16x8*)&As[cur][(wr + mi * 16 + lr) * 32 + lk];
    #pragma unroll
    for (int ni = 0; ni < 2; ++ni)
      bfr[ni] = *(const bf16x8*)&Bs[cur][(wc + ni * 16 + lr) * 32 + lk];
    __builtin_amdgcn_s_setprio(1);
    #pragma unroll
    for (int mi = 0; mi < 4; ++mi)
      #pragma unroll
      for (int ni = 0; ni < 2; ++ni)
        acc[mi][ni] = MFMA16(af[mi], bfr[ni], acc[mi][ni]);
    __builtin_amdgcn_s_setprio(0);
    cur = (cur == 2) ? 0 : cur + 1;
    pre = (pre == 2) ? 0 : pre + 1;
  }

  #pragma unroll
  for (int ni = 0; ni < 2; ++ni) {
    int col = c0 + wc + ni * 16 + lr;
    float bias = b_out[col];
    #pragma unroll
    for (int mi = 0; mi < 4; ++mi)
      #pragma unroll
      for (int reg = 0; reg < 4; ++reg) {
        int row = r0 + wr + mi * 16 + (lane >> 4) * 4 + reg;
        out[(size_t)row * 512 + col] = acc[mi][ni][reg] + bias;
      }
  }
}

// ---------------------------------------------------------------------------
extern "C" void kernel_launch(void* const* d_in, const int* in_sizes, int n_in,
                              void* d_out, int out_size, void* d_ws, size_t ws_size,
                              hipStream_t stream) {
  const float* img       = (const float*)d_in[0];
  const float* tab       = (const float*)d_in[1];
  const float* w_qkv     = (const float*)d_in[2];
  const float* w_tab_qkv = (const float*)d_in[3];
  const float* w_out     = (const float*)d_in[4];
  const float* b_out     = (const float*)d_in[5];
  const float* ln_w      = (const float*)d_in[6];
  const float* ln_b      = (const float*)d_in[7];
  char* ws = (char*)d_ws;
  unsigned short* x_bf = (unsigned short*)(ws);             //  8 MiB
  unsigned short* wqt  = (unsigned short*)(ws + 8388608);   //  1.5 MiB
  unsigned short* wot  = (unsigned short*)(ws + 9961472);   //  0.5 MiB
  unsigned short* qh   = (unsigned short*)(ws + 10485760);  //  8 MiB
  unsigned short* kh   = (unsigned short*)(ws + 18874368);  //  8.5 MiB (KPAD)
  unsigned short* vt   = (unsigned short*)(ws + 27787264);  //  8.5 MiB (KPAD)
  unsigned short* ao   = (unsigned short*)(ws + 36700160);  //  8 MiB
  float* out = (float*)d_out;

  hipLaunchKernelGGL(k_pre,  dim3(2432), dim3(256), 0, stream,
                     img, tab, w_qkv, w_tab_qkv, w_out, ln_w, ln_b,
                     x_bf, wqt, wot, kh, vt);
  hipLaunchKernelGGL(k_qkv,  dim3(192),  dim3(512), 0, stream, x_bf, wqt, qh, kh, vt);
  hipLaunchKernelGGL(k_attn, dim3(256),  dim3(512), 0, stream, qh, kh, vt, ao);
  hipLaunchKernelGGL(k_out,  dim3(256),  dim3(512), 0, stream, ao, wot, b_out, out);
}

// Round 14
// 84.034 us; speedup vs baseline: 1.2419x; 1.2419x over previous
//
#include <hip/hip_runtime.h>

// ---------------------------------------------------------------------------
// Attention_43868795961547: LN -> QKV -> MHA(1025 keys) -> proj
// b=8, n=1024, dim=512, heads=8, dh=64. bf16 MFMA, f32 accum.
// Round 14: k_qkv reverted to round-12 (r13's 256^2 tile under-filled the
// grid: 192 blocks < 256 CUs, 1 block/CU). k_attn/k_out -> 256-thr blocks,
// grid x2 -> 2 blocks/CU so a co-resident block runs during barrier drains.
// ---------------------------------------------------------------------------

typedef __attribute__((ext_vector_type(4))) float f32x4;
typedef __attribute__((ext_vector_type(16))) float f32x16;
typedef __attribute__((ext_vector_type(8))) short bf16x8;
typedef __attribute__((ext_vector_type(8))) unsigned short u16x8;

#define MFMA16(a, b, c) __builtin_amdgcn_mfma_f32_16x16x32_bf16(a, b, c, 0, 0, 0)
#define MFMA32(a, b, c) __builtin_amdgcn_mfma_f32_32x32x16_bf16(a, b, c, 0, 0, 0)

#define GLD16(gsrc, ldst)                                                     \
  __builtin_amdgcn_global_load_lds(                                           \
      (const __attribute__((address_space(1))) void*)(gsrc),                  \
      (__attribute__((address_space(3))) void*)(ldst), 16, 0, 0)

#define KPAD 1088   // keys padded: 17 tiles of 64

// Q pre-scale: dots*0.125 in exp2-domain => fold 0.125*log2(e) into Q.
#define QSCALE 0.18033688011112042f

__device__ __forceinline__ unsigned short f2bf(float f) {
  union { float f; unsigned int u; } c; c.f = f;
  unsigned int u = c.u;
  u += 0x7fffu + ((u >> 16) & 1u);   // RNE
  return (unsigned short)(u >> 16);
}

__device__ __forceinline__ unsigned int cvtpk_bf16(float lo, float hi) {
  unsigned int r;
  asm("v_cvt_pk_bf16_f32 %0, %1, %2" : "=v"(r) : "v"(lo), "v"(hi));
  return r;
}

// ---- kernel 1: fused pre-pass --------------------------------------------
__global__ __launch_bounds__(256) void k_pre(const float* __restrict__ img,
                                             const float* __restrict__ tab,
                                             const float* __restrict__ w_qkv,
                                             const float* __restrict__ w_tab,
                                             const float* __restrict__ w_out,
                                             const float* __restrict__ ln_w,
                                             const float* __restrict__ ln_b,
                                             unsigned short* __restrict__ x_bf,
                                             unsigned short* __restrict__ wqt,
                                             unsigned short* __restrict__ wot,
                                             unsigned short* __restrict__ kh,
                                             unsigned short* __restrict__ vt) {
  int blk = blockIdx.x, tid = threadIdx.x;
  if (blk < 256) {
    __shared__ unsigned short tbuf[64][68];
    const float* src;
    unsigned short* dst;
    int k0, n0, ldin;
    if (blk < 192) {
      int ti = blk / 24, tj = blk % 24;
      k0 = ti * 64; n0 = tj * 64; ldin = 1536;
      src = w_qkv; dst = wqt;
    } else {
      int g = blk - 192;
      int ti = g >> 3, tj = g & 7;
      k0 = ti * 64; n0 = tj * 64; ldin = 512;
      src = w_out; dst = wot;
    }
    int rr = tid >> 4, c4 = (tid & 15) * 4;
    #pragma unroll
    for (int i = 0; i < 4; ++i) {
      int r = i * 16 + rr;
      float4 v = *(const float4*)(src + (size_t)(k0 + r) * ldin + n0 + c4);
      tbuf[c4 + 0][r] = f2bf(v.x);
      tbuf[c4 + 1][r] = f2bf(v.y);
      tbuf[c4 + 2][r] = f2bf(v.z);
      tbuf[c4 + 3][r] = f2bf(v.w);
    }
    __syncthreads();
    #pragma unroll
    for (int i = 0; i < 4; ++i) {
      int r = i * 16 + rr;
      ushort4 w = *(const ushort4*)&tbuf[r][c4];
      *(ushort4*)(dst + (size_t)(n0 + r) * 512 + k0 + c4) = w;
    }
  } else if (blk < 2304) {
    int wid = tid >> 6, lane = tid & 63;
    int row = (blk - 256) * 4 + wid;
    const float* src = img + (size_t)row * 512;
    float4 v0 = *(const float4*)(src + lane * 8);
    float4 v1 = *(const float4*)(src + lane * 8 + 4);
    float x[8] = {v0.x, v0.y, v0.z, v0.w, v1.x, v1.y, v1.z, v1.w};
    float s = 0.f, sq = 0.f;
    #pragma unroll
    for (int j = 0; j < 8; ++j) { s += x[j]; sq += x[j] * x[j]; }
    #pragma unroll
    for (int off = 32; off >= 1; off >>= 1) {
      s  += __shfl_xor(s, off);
      sq += __shfl_xor(sq, off);
    }
    float mean = s * (1.0f / 512.0f);
    float var  = sq * (1.0f / 512.0f) - mean * mean;
    float rs = rsqrtf(var + 1e-5f);
    float4 w0 = *(const float4*)(ln_w + lane * 8);
    float4 w1 = *(const float4*)(ln_w + lane * 8 + 4);
    float4 b0 = *(const float4*)(ln_b + lane * 8);
    float4 b1 = *(const float4*)(ln_b + lane * 8 + 4);
    float w[8] = {w0.x, w0.y, w0.z, w0.w, w1.x, w1.y, w1.z, w1.w};
    float bb[8] = {b0.x, b0.y, b0.z, b0.w, b1.x, b1.y, b1.z, b1.w};
    bf16x8 o;
    #pragma unroll
    for (int j = 0; j < 8; ++j)
      o[j] = (short)f2bf((x[j] - mean) * rs * w[j] + bb[j]);
    *(bf16x8*)(x_bf + (size_t)row * 512 + lane * 8) = o;
  } else {
    __shared__ float tl[512];
    __shared__ float red[4][64];
    __shared__ float ws_[4], wq_[4];
    int blk2 = blk - 2304;           // 128 blocks
    int b = blk2 >> 4, chunk = blk2 & 15;
    int t = tid;
    int lane = t & 63, wid = t >> 6;
    int cl = t & 63;
    int ks = t >> 6;
    int col = chunk * 64 + cl;

    {
      int h = chunk & 7;
      int bh = b * 8 + h;
      u16x8 z = (u16x8)(0);
      if (chunk < 8) {
        unsigned short* base = kh + ((size_t)bh * KPAD + 1024) * 64;
        #pragma unroll
        for (int i = 0; i < 2; ++i)
          *(u16x8*)(base + (t + i * 256) * 8) = z;
      } else {
        #pragma unroll
        for (int i = 0; i < 2; ++i) {
          int idx = t + i * 256;
          int d = idx >> 3, ch = idx & 7;
          *(u16x8*)(vt + ((size_t)bh * 64 + d) * KPAD + 1024 + ch * 8) = z;
        }
      }
    }

    float2 tv = *(const float2*)(tab + (size_t)b * 512 + t * 2);
    float s_ = tv.x + tv.y, q_ = tv.x * tv.x + tv.y * tv.y;
    #pragma unroll
    for (int off = 32; off >= 1; off >>= 1) {
      s_ += __shfl_xor(s_, off);
      q_ += __shfl_xor(q_, off);
    }
    if (lane == 0) { ws_[wid] = s_; wq_[wid] = q_; }
    __syncthreads();
    float S = ws_[0] + ws_[1] + ws_[2] + ws_[3];
    float Qq = wq_[0] + wq_[1] + wq_[2] + wq_[3];
    float mean = S * (1.0f / 512.0f);
    float var = Qq * (1.0f / 512.0f) - mean * mean;
    float rs = rsqrtf(var + 1e-5f);
    tl[t * 2 + 0] = (tv.x - mean) * rs * ln_w[t * 2 + 0] + ln_b[t * 2 + 0];
    tl[t * 2 + 1] = (tv.y - mean) * rs * ln_w[t * 2 + 1] + ln_b[t * 2 + 1];
    __syncthreads();

    const float* wp = w_tab + 512 + col + (size_t)(ks * 128) * 1536;
    float s = 0.f;
    #pragma unroll 8
    for (int k = 0; k < 128; ++k)
      s += tl[ks * 128 + k] * wp[(size_t)k * 1536];
    red[ks][cl] = s;
    __syncthreads();
    if (ks == 0) {
      float v = red[0][cl] + red[1][cl] + red[2][cl] + red[3][cl];
      int part = col >> 9, hd = col & 511, h = hd >> 6, d = hd & 63;
      int bh = b * 8 + h;
      unsigned short hv = f2bf(v);
      if (part == 0) kh[((size_t)bh * KPAD + 1024) * 64 + d] = hv;
      else           vt[((size_t)bh * 64 + d) * KPAD + 1024] = hv;
    }
  }
}

// ---- kernel 4: QKV GEMM, 8 waves (64x32/wave), 3-ring, counted vmcnt ------
// (round-12 version, last good)
__global__ __launch_bounds__(512, 6) void k_qkv(const unsigned short* __restrict__ x_bf,
                                                const unsigned short* __restrict__ wqt,
                                                unsigned short* __restrict__ qh,
                                                unsigned short* __restrict__ kh,
                                                unsigned short* __restrict__ vt) {
  __shared__ unsigned short As[3][128 * 32];
  __shared__ unsigned short Bs[3][128 * 32];
  int tid = threadIdx.x;                    // 0..511
  int wid = tid >> 6, lane = tid & 63;
  int bm = blockIdx.x & 63, bn = blockIdx.x >> 6;   // 64 x 12
  int r0 = bm * 128, c0 = bn * 128;
  int lr = lane & 15, lk = (lane >> 4) * 8;
  int wr = (wid >> 2) * 64, wc = (wid & 3) * 32;    // 2M x 4N wave grid
  int srow = tid >> 2, scol = (tid & 3) * 8;        // 1 x 16B per matrix/thread
  const unsigned short* gA = x_bf + (size_t)(r0 + srow) * 512 + scol;
  const unsigned short* gB = wqt  + (size_t)(c0 + srow) * 512 + scol;
  int ldsoff = tid * 8;                     // linear dest (shorts)

  f32x4 acc[4][2];
  #pragma unroll
  for (int mi = 0; mi < 4; ++mi)
    #pragma unroll
    for (int ni = 0; ni < 2; ++ni)
      acc[mi][ni] = (f32x4){0.f, 0.f, 0.f, 0.f};

  GLD16(gA,      &As[0][ldsoff]);
  GLD16(gB,      &Bs[0][ldsoff]);
  GLD16(gA + 32, &As[1][ldsoff]);
  GLD16(gB + 32, &Bs[1][ldsoff]);

  int cur = 0, pre = 2;
  for (int t = 0; t < 16; ++t) {
    if (t < 15) asm volatile("s_waitcnt vmcnt(2)" ::: "memory");
    else        asm volatile("s_waitcnt vmcnt(0)" ::: "memory");
    __builtin_amdgcn_s_barrier();           // tile t resident block-wide
    if (t < 14) {
      int k2 = (t + 2) * 32;
      GLD16(gA + k2, &As[pre][ldsoff]);
      GLD16(gB + k2, &Bs[pre][ldsoff]);
    }
    bf16x8 af[4], bfr[2];
    #pragma unroll
    for (int mi = 0; mi < 4; ++mi)
      af[mi] = *(const bf16x8*)&As[cur][(wr + mi * 16 + lr) * 32 + lk];
    #pragma unroll
    for (int ni = 0; ni < 2; ++ni)
      bfr[ni] = *(const bf16x8*)&Bs[cur][(wc + ni * 16 + lr) * 32 + lk];
    __builtin_amdgcn_s_setprio(1);
    #pragma unroll
    for (int mi = 0; mi < 4; ++mi)
      #pragma unroll
      for (int ni = 0; ni < 2; ++ni)
        acc[mi][ni] = MFMA16(af[mi], bfr[ni], acc[mi][ni]);
    __builtin_amdgcn_s_setprio(0);
    cur = (cur == 2) ? 0 : cur + 1;
    pre = (pre == 2) ? 0 : pre + 1;
  }

  #pragma unroll
  for (int ni = 0; ni < 2; ++ni) {
    int col0 = c0 + wc + ni * 16;
    int which = col0 >> 9;
    int hh = (col0 & 511) >> 6;
    int d = (col0 & 63) + lr;
    #pragma unroll
    for (int mi = 0; mi < 4; ++mi)
      #pragma unroll
      for (int reg = 0; reg < 4; ++reg) {
        int row = r0 + wr + mi * 16 + (lane >> 4) * 4 + reg;
        int b = row >> 10, n = row & 1023;
        int bh = b * 8 + hh;
        float v = acc[mi][ni][reg];
        if (which == 0) {
          qh[((size_t)bh * 1024 + n) * 64 + d] = f2bf(v * QSCALE);
        } else if (which == 1) {
          kh[((size_t)bh * KPAD + n) * 64 + d] = f2bf(v);
        } else {
          vt[((size_t)bh * 64 + d) * KPAD + n] = f2bf(v);
        }
      }
  }
}

// ---- kernel 5: flash attention, 4-wave blocks, 2 blocks/CU ----------------
// 512 blocks x 256 thr. Block = (bh, 128-q-row segment); wave = 32 q-rows.
// K/V 64-key tiles staged to LDS (double-buffered, XOR-swizzled source).
__global__ __launch_bounds__(256, 4) void k_attn(const unsigned short* __restrict__ qh,
                                                 const unsigned short* __restrict__ kh,
                                                 const unsigned short* __restrict__ vt,
                                                 unsigned short* __restrict__ ao) {
  __shared__ __align__(16) unsigned short Ks[2][4096];  // [64 key][64 d] swz
  __shared__ __align__(16) unsigned short Vs[2][4096];  // [64 d][64 key] swz
  int tid = threadIdx.x;
  int wid = tid >> 6, lane = tid & 63;
  int bid = blockIdx.x;
  int swz = ((bid & 7) << 6) | (bid >> 3);   // bijective (512%8==0); 8 bh/XCD
  int bh = swz >> 3;
  int q0 = (swz & 7) * 128 + wid * 32;
  int lq = lane & 31, half = lane >> 5;

  const unsigned short* Q  = qh + (size_t)bh * 1024 * 64;
  const unsigned short* Kg = kh + (size_t)bh * KPAD * 64;
  const unsigned short* Vg = vt + (size_t)bh * 64 * KPAD;

  // staging: 2 chunks per matrix per thread. id = i*256+tid; row=id>>3,
  // chunk c = (id&7) ^ (row&7) (involution; row+32 keeps same c).
  int xr = tid >> 3;                         // 0..31
  int xc = (tid & 7) ^ (xr & 7);
  const unsigned short* kg0 = Kg + xr * 64 + xc * 8;
  const unsigned short* kg1 = kg0 + 32 * 64;
  const unsigned short* vg0 = Vg + (size_t)xr * KPAD + xc * 8;
  const unsigned short* vg1 = vg0 + (size_t)32 * KPAD;

  bf16x8 qf[4];
  const unsigned short* qlane = Q + (size_t)(q0 + lq) * 64 + half * 8;
  #pragma unroll
  for (int dt = 0; dt < 4; ++dt)
    qf[dt] = *(const bf16x8*)(qlane + dt * 16);

  f32x16 o0 = (f32x16)(0.0f), o1 = (f32x16)(0.0f);
  float m = -1e30f, lsum = 0.f;

  // prologue: tile 0 into buffer 0
  GLD16(kg0, &Ks[0][wid * 512]);
  GLD16(kg1, &Ks[0][2048 + wid * 512]);
  GLD16(vg0, &Vs[0][wid * 512]);
  GLD16(vg1, &Vs[0][2048 + wid * 512]);
  __syncthreads();

  for (int kt = 0; kt < 17; ++kt) {
    int cur = kt & 1;
    if (kt < 16) {
      int nxt = cur ^ 1;
      GLD16(kg0 + (kt + 1) * 4096, &Ks[nxt][wid * 512]);
      GLD16(kg1 + (kt + 1) * 4096, &Ks[nxt][2048 + wid * 512]);
      GLD16(vg0 + (kt + 1) * 64,   &Vs[nxt][wid * 512]);
      GLD16(vg1 + (kt + 1) * 64,   &Vs[nxt][2048 + wid * 512]);
    }
    const unsigned short* Kb = Ks[cur];
    const unsigned short* Vb = Vs[cur];
    #pragma unroll
    for (int sub = 0; sub < 2; ++sub) {
      int krow = sub * 32 + lq;
      bf16x8 kf[4];
      #pragma unroll
      for (int dt = 0; dt < 4; ++dt) {
        int ch = (half + dt * 2) ^ (krow & 7);
        kf[dt] = *(const bf16x8*)&Kb[krow * 64 + ch * 8];
      }
      f32x16 s = (f32x16)(0.0f);
      __builtin_amdgcn_s_setprio(1);
      #pragma unroll
      for (int dt = 0; dt < 4; ++dt)
        s = MFMA32(kf[dt], qf[dt], s);
      __builtin_amdgcn_s_setprio(0);
      if (kt == 16) {
        if (sub == 0) {
          #pragma unroll
          for (int reg = 0; reg < 16; ++reg) {
            if (reg == 0) { if (half) s[0] = -1e30f; }
            else s[reg] = -1e30f;
          }
        } else {
          #pragma unroll
          for (int reg = 0; reg < 16; ++reg) s[reg] = -1e30f;
        }
      }
      float pmax = s[0];
      #pragma unroll
      for (int reg = 1; reg < 16; ++reg) pmax = fmaxf(pmax, s[reg]);
      pmax = fmaxf(pmax, __shfl_xor(pmax, 32));
      if (!__all(pmax <= m + 8.0f)) {
        float mnew = fmaxf(m, pmax);
        float al = __builtin_amdgcn_exp2f(m - mnew);
        lsum *= al;
        #pragma unroll
        for (int reg = 0; reg < 16; ++reg) { o0[reg] *= al; o1[reg] *= al; }
        m = mnew;
      }
      float p[16];
      float ls = 0.f;
      #pragma unroll
      for (int reg = 0; reg < 16; ++reg) {
        p[reg] = __builtin_amdgcn_exp2f(s[reg] - m);
        ls += p[reg];
      }
      lsum += ls;
      unsigned int c0x0 = cvtpk_bf16(p[0],  p[1]);
      unsigned int c0x1 = cvtpk_bf16(p[2],  p[3]);
      unsigned int c0y0 = cvtpk_bf16(p[4],  p[5]);
      unsigned int c0y1 = cvtpk_bf16(p[6],  p[7]);
      unsigned int c1x0 = cvtpk_bf16(p[8],  p[9]);
      unsigned int c1x1 = cvtpk_bf16(p[10], p[11]);
      unsigned int c1y0 = cvtpk_bf16(p[12], p[13]);
      unsigned int c1y1 = cvtpk_bf16(p[14], p[15]);
      asm volatile("v_permlane32_swap_b32 %0, %1" : "+v"(c0x0), "+v"(c0y0));
      asm volatile("v_permlane32_swap_b32 %0, %1" : "+v"(c0x1), "+v"(c0y1));
      asm volatile("v_permlane32_swap_b32 %0, %1" : "+v"(c1x0), "+v"(c1y0));
      asm volatile("v_permlane32_swap_b32 %0, %1" : "+v"(c1x1), "+v"(c1y1));
      union { unsigned int w[4]; bf16x8 v; } f0, f1;
      f0.w[0] = c0x0; f0.w[1] = c0x1; f0.w[2] = c0y0; f0.w[3] = c0y1;
      f1.w[0] = c1x0; f1.w[1] = c1x1; f1.w[2] = c1y0; f1.w[3] = c1y1;
      int vr0 = lq, vr1 = lq + 32;
      int cb = sub * 4 + half;
      bf16x8 vf0 = *(const bf16x8*)&Vb[vr0 * 64 + ((cb + 0) ^ (vr0 & 7)) * 8];
      bf16x8 vf1 = *(const bf16x8*)&Vb[vr0 * 64 + ((cb + 2) ^ (vr0 & 7)) * 8];
      bf16x8 vf2 = *(const bf16x8*)&Vb[vr1 * 64 + ((cb + 0) ^ (vr1 & 7)) * 8];
      bf16x8 vf3 = *(const bf16x8*)&Vb[vr1 * 64 + ((cb + 2) ^ (vr1 & 7)) * 8];
      __builtin_amdgcn_s_setprio(1);
      o0 = MFMA32(vf0, f0.v, o0);
      o0 = MFMA32(vf1, f1.v, o0);
      o1 = MFMA32(vf2, f0.v, o1);
      o1 = MFMA32(vf3, f1.v, o1);
      __builtin_amdgcn_s_setprio(0);
    }
    __syncthreads();
  }
  lsum += __shfl_xor(lsum, 32);
  float rl = 1.0f / lsum;
  int b = bh >> 3, h = bh & 7;
  unsigned short* aorow = ao + ((size_t)(b * 1024 + q0 + lq)) * 512 + h * 64;
  #pragma unroll
  for (int dt2 = 0; dt2 < 2; ++dt2) {
    #pragma unroll
    for (int g = 0; g < 4; ++g) {
      ushort4 pk;
      float v0 = (dt2 ? o1[4 * g + 0] : o0[4 * g + 0]) * rl;
      float v1 = (dt2 ? o1[4 * g + 1] : o0[4 * g + 1]) * rl;
      float v2 = (dt2 ? o1[4 * g + 2] : o0[4 * g + 2]) * rl;
      float v3 = (dt2 ? o1[4 * g + 3] : o0[4 * g + 3]) * rl;
      pk.x = f2bf(v0); pk.y = f2bf(v1); pk.z = f2bf(v2); pk.w = f2bf(v3);
      *(ushort4*)(aorow + dt2 * 32 + 8 * g + 4 * half) = pk;
    }
  }
}

// ---- kernel 6: output GEMM + bias, 4-wave blocks (128x64 tile) ------------
// 512 blocks (64 x 8) x 256 thr; wave tile 64x32 (2M x 2N). 3-ring LDS,
// counted vmcnt(3) (per-thread 3 loads/tile: 2 A + 1 B).
__global__ __launch_bounds__(256, 4) void k_out(const unsigned short* __restrict__ ao,
                                                const unsigned short* __restrict__ wot,
                                                const float* __restrict__ b_out,
                                                float* __restrict__ out) {
  __shared__ unsigned short As[3][128 * 32];
  __shared__ unsigned short Bs[3][64 * 32];
  int tid = threadIdx.x;
  int wid = tid >> 6, lane = tid & 63;
  int bm = blockIdx.x & 63, bn = blockIdx.x >> 6;   // 64 x 8
  int r0 = bm * 128, c0 = bn * 64;
  int lr = lane & 15, lk = (lane >> 4) * 8;
  int wr = (wid >> 1) * 64, wc = (wid & 1) * 32;    // 2M x 2N
  int srowA0 = tid >> 2, srowA1 = 64 + (tid >> 2), scol = (tid & 3) * 8;
  const unsigned short* gA0 = ao  + (size_t)(r0 + srowA0) * 512 + scol;
  const unsigned short* gA1 = ao  + (size_t)(r0 + srowA1) * 512 + scol;
  const unsigned short* gB  = wot + (size_t)(c0 + srowA0) * 512 + scol;  // rows 0..63
  int offA0 = tid * 8, offA1 = 2048 + tid * 8, offB = tid * 8;

  f32x4 acc[4][2];
  #pragma unroll
  for (int mi = 0; mi < 4; ++mi)
    #pragma unroll
    for (int ni = 0; ni < 2; ++ni)
      acc[mi][ni] = (f32x4){0.f, 0.f, 0.f, 0.f};

  // prologue: tiles 0 and 1 (per-thread 3 loads each, issue order = age)
  GLD16(gA0,      &As[0][offA0]);
  GLD16(gA1,      &As[0][offA1]);
  GLD16(gB,       &Bs[0][offB]);
  GLD16(gA0 + 32, &As[1][offA0]);
  GLD16(gA1 + 32, &As[1][offA1]);
  GLD16(gB  + 32, &Bs[1][offB]);

  int cur = 0, pre = 2;
  for (int t = 0; t < 16; ++t) {
    if (t < 15) asm volatile("s_waitcnt vmcnt(3)" ::: "memory");
    else        asm volatile("s_waitcnt vmcnt(0)" ::: "memory");
    __builtin_amdgcn_s_barrier();
    if (t < 14) {
      int k2 = (t + 2) * 32;
      GLD16(gA0 + k2, &As[pre][offA0]);
      GLD16(gA1 + k2, &As[pre][offA1]);
      GLD16(gB  + k2, &Bs[pre][offB]);
    }
    bf16x8 af[4], bfr[2];
    #pragma unroll
    for (int mi = 0; mi < 4; ++mi)
      af[mi] = *(const bf16x8*)&As[cur][(wr + mi * 16 + lr) * 32 + lk];
    #pragma unroll
    for (int ni = 0; ni < 2; ++ni)
      bfr[ni] = *(const bf16x8*)&Bs[cur][(wc + ni * 16 + lr) * 32 + lk];
    __builtin_amdgcn_s_setprio(1);
    #pragma unroll
    for (int mi = 0; mi < 4; ++mi)
      #pragma unroll
      for (int ni = 0; ni < 2; ++ni)
        acc[mi][ni] = MFMA16(af[mi], bfr[ni], acc[mi][ni]);
    __builtin_amdgcn_s_setprio(0);
    cur = (cur == 2) ? 0 : cur + 1;
    pre = (pre == 2) ? 0 : pre + 1;
  }

  #pragma unroll
  for (int ni = 0; ni < 2; ++ni) {
    int col = c0 + wc + ni * 16 + lr;
    float bias = b_out[col];
    #pragma unroll
    for (int mi = 0; mi < 4; ++mi)
      #pragma unroll
      for (int reg = 0; reg < 4; ++reg) {
        int row = r0 + wr + mi * 16 + (lane >> 4) * 4 + reg;
        out[(size_t)row * 512 + col] = acc[mi][ni][reg] + bias;
      }
  }
}

// ---------------------------------------------------------------------------
extern "C" void kernel_launch(void* const* d_in, const int* in_sizes, int n_in,
                              void* d_out, int out_size, void* d_ws, size_t ws_size,
                              hipStream_t stream) {
  const float* img       = (const float*)d_in[0];
  const float* tab       = (const float*)d_in[1];
  const float* w_qkv     = (const float*)d_in[2];
  const float* w_tab_qkv = (const float*)d_in[3];
  const float* w_out     = (const float*)d_in[4];
  const float* b_out     = (const float*)d_in[5];
  const float* ln_w      = (const float*)d_in[6];
  const float* ln_b      = (const float*)d_in[7];
  char* ws = (char*)d_ws;
  unsigned short* x_bf = (unsigned short*)(ws);             //  8 MiB
  unsigned short* wqt  = (unsigned short*)(ws + 8388608);   //  1.5 MiB
  unsigned short* wot  = (unsigned short*)(ws + 9961472);   //  0.5 MiB
  unsigned short* qh   = (unsigned short*)(ws + 10485760);  //  8 MiB
  unsigned short* kh   = (unsigned short*)(ws + 18874368);  //  8.5 MiB (KPAD)
  unsigned short* vt   = (unsigned short*)(ws + 27787264);  //  8.5 MiB (KPAD)
  unsigned short* ao   = (unsigned short*)(ws + 36700160);  //  8 MiB
  float* out = (float*)d_out;

  hipLaunchKernelGGL(k_pre,  dim3(2432), dim3(256), 0, stream,
                     img, tab, w_qkv, w_tab_qkv, w_out, ln_w, ln_b,
                     x_bf, wqt, wot, kh, vt);
  hipLaunchKernelGGL(k_qkv,  dim3(768),  dim3(512), 0, stream, x_bf, wqt, qh, kh, vt);
  hipLaunchKernelGGL(k_attn, dim3(512),  dim3(256), 0, stream, qh, kh, vt, ao);
  hipLaunchKernelGGL(k_out,  dim3(512),  dim3(256), 0, stream, ao, wot, b_out, out);
}

// Round 15
// 82.241 us; speedup vs baseline: 1.2690x; 1.0218x over previous
//
#include <hip/hip_runtime.h>

// ---------------------------------------------------------------------------
// Attention_43868795961547: LN -> QKV -> MHA(1025 keys) -> proj
// b=8, n=1024, dim=512, heads=8, dh=64. bf16 MFMA, f32 accum.
// Round 15: k_attn/k_out reverted to round-12 (best, 82.5us). Single change:
// k_qkv BK=32 -> 64 (128x128 tile kept): 16 MFMA/wave per barrier-pair, 8
// steps, 64KB LDS (2 blocks/CU), XOR-swizzled rows (r13-proven involution),
// counted vmcnt(4).
// ---------------------------------------------------------------------------

typedef __attribute__((ext_vector_type(4))) float f32x4;
typedef __attribute__((ext_vector_type(16))) float f32x16;
typedef __attribute__((ext_vector_type(8))) short bf16x8;
typedef __attribute__((ext_vector_type(8))) unsigned short u16x8;

#define MFMA16(a, b, c) __builtin_amdgcn_mfma_f32_16x16x32_bf16(a, b, c, 0, 0, 0)
#define MFMA32(a, b, c) __builtin_amdgcn_mfma_f32_32x32x16_bf16(a, b, c, 0, 0, 0)

#define GLD16(gsrc, ldst)                                                     \
  __builtin_amdgcn_global_load_lds(                                           \
      (const __attribute__((address_space(1))) void*)(gsrc),                  \
      (__attribute__((address_space(3))) void*)(ldst), 16, 0, 0)

#define KPAD 1088   // keys padded: 17 tiles of 64

// Q pre-scale: dots*0.125 in exp2-domain => fold 0.125*log2(e) into Q.
#define QSCALE 0.18033688011112042f

__device__ __forceinline__ unsigned short f2bf(float f) {
  union { float f; unsigned int u; } c; c.f = f;
  unsigned int u = c.u;
  u += 0x7fffu + ((u >> 16) & 1u);   // RNE
  return (unsigned short)(u >> 16);
}

__device__ __forceinline__ unsigned int cvtpk_bf16(float lo, float hi) {
  unsigned int r;
  asm("v_cvt_pk_bf16_f32 %0, %1, %2" : "=v"(r) : "v"(lo), "v"(hi));
  return r;
}

// ---- kernel 1: fused pre-pass --------------------------------------------
__global__ __launch_bounds__(256) void k_pre(const float* __restrict__ img,
                                             const float* __restrict__ tab,
                                             const float* __restrict__ w_qkv,
                                             const float* __restrict__ w_tab,
                                             const float* __restrict__ w_out,
                                             const float* __restrict__ ln_w,
                                             const float* __restrict__ ln_b,
                                             unsigned short* __restrict__ x_bf,
                                             unsigned short* __restrict__ wqt,
                                             unsigned short* __restrict__ wot,
                                             unsigned short* __restrict__ kh,
                                             unsigned short* __restrict__ vt) {
  int blk = blockIdx.x, tid = threadIdx.x;
  if (blk < 256) {
    __shared__ unsigned short tbuf[64][68];
    const float* src;
    unsigned short* dst;
    int k0, n0, ldin;
    if (blk < 192) {
      int ti = blk / 24, tj = blk % 24;
      k0 = ti * 64; n0 = tj * 64; ldin = 1536;
      src = w_qkv; dst = wqt;
    } else {
      int g = blk - 192;
      int ti = g >> 3, tj = g & 7;
      k0 = ti * 64; n0 = tj * 64; ldin = 512;
      src = w_out; dst = wot;
    }
    int rr = tid >> 4, c4 = (tid & 15) * 4;
    #pragma unroll
    for (int i = 0; i < 4; ++i) {
      int r = i * 16 + rr;
      float4 v = *(const float4*)(src + (size_t)(k0 + r) * ldin + n0 + c4);
      tbuf[c4 + 0][r] = f2bf(v.x);
      tbuf[c4 + 1][r] = f2bf(v.y);
      tbuf[c4 + 2][r] = f2bf(v.z);
      tbuf[c4 + 3][r] = f2bf(v.w);
    }
    __syncthreads();
    #pragma unroll
    for (int i = 0; i < 4; ++i) {
      int r = i * 16 + rr;
      ushort4 w = *(const ushort4*)&tbuf[r][c4];
      *(ushort4*)(dst + (size_t)(n0 + r) * 512 + k0 + c4) = w;
    }
  } else if (blk < 2304) {
    int wid = tid >> 6, lane = tid & 63;
    int row = (blk - 256) * 4 + wid;
    const float* src = img + (size_t)row * 512;
    float4 v0 = *(const float4*)(src + lane * 8);
    float4 v1 = *(const float4*)(src + lane * 8 + 4);
    float x[8] = {v0.x, v0.y, v0.z, v0.w, v1.x, v1.y, v1.z, v1.w};
    float s = 0.f, sq = 0.f;
    #pragma unroll
    for (int j = 0; j < 8; ++j) { s += x[j]; sq += x[j] * x[j]; }
    #pragma unroll
    for (int off = 32; off >= 1; off >>= 1) {
      s  += __shfl_xor(s, off);
      sq += __shfl_xor(sq, off);
    }
    float mean = s * (1.0f / 512.0f);
    float var  = sq * (1.0f / 512.0f) - mean * mean;
    float rs = rsqrtf(var + 1e-5f);
    float4 w0 = *(const float4*)(ln_w + lane * 8);
    float4 w1 = *(const float4*)(ln_w + lane * 8 + 4);
    float4 b0 = *(const float4*)(ln_b + lane * 8);
    float4 b1 = *(const float4*)(ln_b + lane * 8 + 4);
    float w[8] = {w0.x, w0.y, w0.z, w0.w, w1.x, w1.y, w1.z, w1.w};
    float bb[8] = {b0.x, b0.y, b0.z, b0.w, b1.x, b1.y, b1.z, b1.w};
    bf16x8 o;
    #pragma unroll
    for (int j = 0; j < 8; ++j)
      o[j] = (short)f2bf((x[j] - mean) * rs * w[j] + bb[j]);
    *(bf16x8*)(x_bf + (size_t)row * 512 + lane * 8) = o;
  } else {
    __shared__ float tl[512];
    __shared__ float red[4][64];
    __shared__ float ws_[4], wq_[4];
    int blk2 = blk - 2304;           // 128 blocks
    int b = blk2 >> 4, chunk = blk2 & 15;
    int t = tid;
    int lane = t & 63, wid = t >> 6;
    int cl = t & 63;
    int ks = t >> 6;
    int col = chunk * 64 + cl;

    {
      int h = chunk & 7;
      int bh = b * 8 + h;
      u16x8 z = (u16x8)(0);
      if (chunk < 8) {
        unsigned short* base = kh + ((size_t)bh * KPAD + 1024) * 64;
        #pragma unroll
        for (int i = 0; i < 2; ++i)
          *(u16x8*)(base + (t + i * 256) * 8) = z;
      } else {
        #pragma unroll
        for (int i = 0; i < 2; ++i) {
          int idx = t + i * 256;
          int d = idx >> 3, ch = idx & 7;
          *(u16x8*)(vt + ((size_t)bh * 64 + d) * KPAD + 1024 + ch * 8) = z;
        }
      }
    }

    float2 tv = *(const float2*)(tab + (size_t)b * 512 + t * 2);
    float s_ = tv.x + tv.y, q_ = tv.x * tv.x + tv.y * tv.y;
    #pragma unroll
    for (int off = 32; off >= 1; off >>= 1) {
      s_ += __shfl_xor(s_, off);
      q_ += __shfl_xor(q_, off);
    }
    if (lane == 0) { ws_[wid] = s_; wq_[wid] = q_; }
    __syncthreads();
    float S = ws_[0] + ws_[1] + ws_[2] + ws_[3];
    float Qq = wq_[0] + wq_[1] + wq_[2] + wq_[3];
    float mean = S * (1.0f / 512.0f);
    float var = Qq * (1.0f / 512.0f) - mean * mean;
    float rs = rsqrtf(var + 1e-5f);
    tl[t * 2 + 0] = (tv.x - mean) * rs * ln_w[t * 2 + 0] + ln_b[t * 2 + 0];
    tl[t * 2 + 1] = (tv.y - mean) * rs * ln_w[t * 2 + 1] + ln_b[t * 2 + 1];
    __syncthreads();

    const float* wp = w_tab + 512 + col + (size_t)(ks * 128) * 1536;
    float s = 0.f;
    #pragma unroll 8
    for (int k = 0; k < 128; ++k)
      s += tl[ks * 128 + k] * wp[(size_t)k * 1536];
    red[ks][cl] = s;
    __syncthreads();
    if (ks == 0) {
      float v = red[0][cl] + red[1][cl] + red[2][cl] + red[3][cl];
      int part = col >> 9, hd = col & 511, h = hd >> 6, d = hd & 63;
      int bh = b * 8 + h;
      unsigned short hv = f2bf(v);
      if (part == 0) kh[((size_t)bh * KPAD + 1024) * 64 + d] = hv;
      else           vt[((size_t)bh * 64 + d) * KPAD + 1024] = hv;
    }
  }
}

// ---- kernel 4: QKV GEMM, 128x128 tile, BK=64, XOR-swizzled, vmcnt(4) ------
// 768 blocks (64 x 12), 512 thr / 8 waves (2M x 4N), wave tile 64x32.
// LDS 64KB: As/Bs[2][128*64]. Row = 64 bf16 = 8 chunks of 16B; physical
// chunk q = logical c ^ (row&7) (pre-swizzled source, swizzled read).
__global__ __launch_bounds__(512, 4) void k_qkv(const unsigned short* __restrict__ x_bf,
                                                const unsigned short* __restrict__ wqt,
                                                unsigned short* __restrict__ qh,
                                                unsigned short* __restrict__ kh,
                                                unsigned short* __restrict__ vt) {
  __shared__ unsigned short As[2][128 * 64];
  __shared__ unsigned short Bs[2][128 * 64];
  int tid = threadIdx.x;                    // 0..511
  int wid = tid >> 6, lane = tid & 63;
  int bm = blockIdx.x & 63, bn = blockIdx.x >> 6;   // 64 x 12
  int r0 = bm * 128, c0 = bn * 128;
  int lr = lane & 15, hc = lane >> 4;       // fragment row / k-chunk (0..3)
  int wr = (wid >> 2) * 64, wc = (wid & 3) * 32;    // 2M x 4N wave grid

  // staging: 2 chunks per matrix per thread. id = i*512 + tid (0..1023);
  // row = id>>3 (0..127), linear q = id&7, logical c = q ^ (row&7).
  int srow[2], sc[2];
  #pragma unroll
  for (int i = 0; i < 2; ++i) {
    int id = i * 512 + tid;
    srow[i] = id >> 3;
    sc[i] = (id & 7) ^ (srow[i] & 7);
  }

  f32x4 acc[4][2];
  #pragma unroll
  for (int mi = 0; mi < 4; ++mi)
    #pragma unroll
    for (int ni = 0; ni < 2; ++ni)
      acc[mi][ni] = (f32x4){0.f, 0.f, 0.f, 0.f};

  #define STAGE_QKV(kt, buf)                                                   \
    do {                                                                       \
      int kb = (kt) * 64;                                                      \
      _Pragma("unroll")                                                        \
      for (int i = 0; i < 2; ++i)                                              \
        GLD16(x_bf + (size_t)(r0 + srow[i]) * 512 + kb + sc[i] * 8,            \
              &As[buf][(i * 512 + tid) * 8]);                                  \
      _Pragma("unroll")                                                        \
      for (int i = 0; i < 2; ++i)                                              \
        GLD16(wqt + (size_t)(c0 + srow[i]) * 512 + kb + sc[i] * 8,             \
              &Bs[buf][(i * 512 + tid) * 8]);                                  \
    } while (0)

  STAGE_QKV(0, 0);
  STAGE_QKV(1, 1);

  for (int t = 0; t < 8; ++t) {
    int cur = t & 1;
    if (t < 7) asm volatile("s_waitcnt vmcnt(4)" ::: "memory");
    else       asm volatile("s_waitcnt vmcnt(0)" ::: "memory");
    __builtin_amdgcn_s_barrier();           // tile t resident block-wide
    __builtin_amdgcn_sched_barrier(0);
    #pragma unroll
    for (int kk = 0; kk < 2; ++kk) {
      bf16x8 af[4], bfr[2];
      #pragma unroll
      for (int mi = 0; mi < 4; ++mi) {
        int row = wr + mi * 16 + lr;
        int q = (kk * 4 + hc) ^ (row & 7);
        af[mi] = *(const bf16x8*)&As[cur][row * 64 + q * 8];
      }
      #pragma unroll
      for (int ni = 0; ni < 2; ++ni) {
        int row = wc + ni * 16 + lr;
        int q = (kk * 4 + hc) ^ (row & 7);
        bfr[ni] = *(const bf16x8*)&Bs[cur][row * 64 + q * 8];
      }
      __builtin_amdgcn_s_setprio(1);
      #pragma unroll
      for (int mi = 0; mi < 4; ++mi)
        #pragma unroll
        for (int ni = 0; ni < 2; ++ni)
          acc[mi][ni] = MFMA16(af[mi], bfr[ni], acc[mi][ni]);
      __builtin_amdgcn_s_setprio(0);
    }
    __builtin_amdgcn_s_barrier();           // all waves done reading buf[cur]
    __builtin_amdgcn_sched_barrier(0);
    if (t < 6) STAGE_QKV(t + 2, cur);
  }
  #undef STAGE_QKV

  #pragma unroll
  for (int ni = 0; ni < 2; ++ni) {
    int col0 = c0 + wc + ni * 16;
    int which = col0 >> 9;
    int hh = (col0 & 511) >> 6;
    int d = (col0 & 63) + lr;
    #pragma unroll
    for (int mi = 0; mi < 4; ++mi)
      #pragma unroll
      for (int reg = 0; reg < 4; ++reg) {
        int row = r0 + wr + mi * 16 + (lane >> 4) * 4 + reg;
        int b = row >> 10, n = row & 1023;
        int bh = b * 8 + hh;
        float v = acc[mi][ni][reg];
        if (which == 0) {
          qh[((size_t)bh * 1024 + n) * 64 + d] = f2bf(v * QSCALE);
        } else if (which == 1) {
          kh[((size_t)bh * KPAD + n) * 64 + d] = f2bf(v);
        } else {
          vt[((size_t)bh * 64 + d) * KPAD + n] = f2bf(v);
        }
      }
  }
}

// ---- kernel 5: flash attention, 8-wave block + LDS-staged K/V (r12) -------
__global__ __launch_bounds__(512, 4) void k_attn(const unsigned short* __restrict__ qh,
                                                 const unsigned short* __restrict__ kh,
                                                 const unsigned short* __restrict__ vt,
                                                 unsigned short* __restrict__ ao) {
  __shared__ __align__(16) unsigned short Ks[2][4096];  // [64 key][64 d] swz
  __shared__ __align__(16) unsigned short Vs[2][4096];  // [64 d][64 key] swz
  int tid = threadIdx.x;
  int wid = tid >> 6, lane = tid & 63;
  int bid = blockIdx.x;
  int swz = ((bid & 7) << 5) | (bid >> 3);   // bijective; 8 bh per XCD
  int bh = swz >> 2;
  int q0 = (swz & 3) * 256 + wid * 32;
  int lq = lane & 31, half = lane >> 5;

  const unsigned short* Q  = qh + (size_t)bh * 1024 * 64;
  const unsigned short* Kg = kh + (size_t)bh * KPAD * 64;
  const unsigned short* Vg = vt + (size_t)bh * 64 * KPAD;

  int xr = tid >> 3;
  int xc = (tid & 7) ^ (xr & 7);
  const unsigned short* kg_src = Kg + xr * 64 + xc * 8;
  const unsigned short* vg_src = Vg + (size_t)xr * KPAD + xc * 8;
  unsigned short* kdstA = &Ks[0][wid * 512];
  unsigned short* kdstB = &Ks[1][wid * 512];
  unsigned short* vdstA = &Vs[0][wid * 512];
  unsigned short* vdstB = &Vs[1][wid * 512];

  bf16x8 qf[4];
  const unsigned short* qlane = Q + (size_t)(q0 + lq) * 64 + half * 8;
  #pragma unroll
  for (int dt = 0; dt < 4; ++dt)
    qf[dt] = *(const bf16x8*)(qlane + dt * 16);

  f32x16 o0 = (f32x16)(0.0f), o1 = (f32x16)(0.0f);
  float m = -1e30f, lsum = 0.f;

  GLD16(kg_src, kdstA);
  GLD16(vg_src, vdstA);
  __syncthreads();

  for (int kt = 0; kt < 17; ++kt) {
    int cur = kt & 1;
    if (kt < 16) {
      GLD16(kg_src + (kt + 1) * 4096, cur ? kdstA : kdstB);
      GLD16(vg_src + (kt + 1) * 64,   cur ? vdstA : vdstB);
    }
    const unsigned short* Kb = Ks[cur];
    const unsigned short* Vb = Vs[cur];
    #pragma unroll
    for (int sub = 0; sub < 2; ++sub) {
      int krow = sub * 32 + lq;
      bf16x8 kf[4];
      #pragma unroll
      for (int dt = 0; dt < 4; ++dt) {
        int ch = (half + dt * 2) ^ (krow & 7);
        kf[dt] = *(const bf16x8*)&Kb[krow * 64 + ch * 8];
      }
      f32x16 s = (f32x16)(0.0f);
      __builtin_amdgcn_s_setprio(1);
      #pragma unroll
      for (int dt = 0; dt < 4; ++dt)
        s = MFMA32(kf[dt], qf[dt], s);
      __builtin_amdgcn_s_setprio(0);
      if (kt == 16) {
        if (sub == 0) {
          #pragma unroll
          for (int reg = 0; reg < 16; ++reg) {
            if (reg == 0) { if (half) s[0] = -1e30f; }
            else s[reg] = -1e30f;
          }
        } else {
          #pragma unroll
          for (int reg = 0; reg < 16; ++reg) s[reg] = -1e30f;
        }
      }
      float pmax = s[0];
      #pragma unroll
      for (int reg = 1; reg < 16; ++reg) pmax = fmaxf(pmax, s[reg]);
      pmax = fmaxf(pmax, __shfl_xor(pmax, 32));
      if (!__all(pmax <= m + 8.0f)) {
        float mnew = fmaxf(m, pmax);
        float al = __builtin_amdgcn_exp2f(m - mnew);
        lsum *= al;
        #pragma unroll
        for (int reg = 0; reg < 16; ++reg) { o0[reg] *= al; o1[reg] *= al; }
        m = mnew;
      }
      float p[16];
      float ls = 0.f;
      #pragma unroll
      for (int reg = 0; reg < 16; ++reg) {
        p[reg] = __builtin_amdgcn_exp2f(s[reg] - m);
        ls += p[reg];
      }
      lsum += ls;
      unsigned int c0x0 = cvtpk_bf16(p[0],  p[1]);
      unsigned int c0x1 = cvtpk_bf16(p[2],  p[3]);
      unsigned int c0y0 = cvtpk_bf16(p[4],  p[5]);
      unsigned int c0y1 = cvtpk_bf16(p[6],  p[7]);
      unsigned int c1x0 = cvtpk_bf16(p[8],  p[9]);
      unsigned int c1x1 = cvtpk_bf16(p[10], p[11]);
      unsigned int c1y0 = cvtpk_bf16(p[12], p[13]);
      unsigned int c1y1 = cvtpk_bf16(p[14], p[15]);
      asm volatile("v_permlane32_swap_b32 %0, %1" : "+v"(c0x0), "+v"(c0y0));
      asm volatile("v_permlane32_swap_b32 %0, %1" : "+v"(c0x1), "+v"(c0y1));
      asm volatile("v_permlane32_swap_b32 %0, %1" : "+v"(c1x0), "+v"(c1y0));
      asm volatile("v_permlane32_swap_b32 %0, %1" : "+v"(c1x1), "+v"(c1y1));
      union { unsigned int w[4]; bf16x8 v; } f0, f1;
      f0.w[0] = c0x0; f0.w[1] = c0x1; f0.w[2] = c0y0; f0.w[3] = c0y1;
      f1.w[0] = c1x0; f1.w[1] = c1x1; f1.w[2] = c1y0; f1.w[3] = c1y1;
      int vr0 = lq, vr1 = lq + 32;
      int cb = sub * 4 + half;
      bf16x8 vf0 = *(const bf16x8*)&Vb[vr0 * 64 + ((cb + 0) ^ (vr0 & 7)) * 8];
      bf16x8 vf1 = *(const bf16x8*)&Vb[vr0 * 64 + ((cb + 2) ^ (vr0 & 7)) * 8];
      bf16x8 vf2 = *(const bf16x8*)&Vb[vr1 * 64 + ((cb + 0) ^ (vr1 & 7)) * 8];
      bf16x8 vf3 = *(const bf16x8*)&Vb[vr1 * 64 + ((cb + 2) ^ (vr1 & 7)) * 8];
      __builtin_amdgcn_s_setprio(1);
      o0 = MFMA32(vf0, f0.v, o0);
      o0 = MFMA32(vf1, f1.v, o0);
      o1 = MFMA32(vf2, f0.v, o1);
      o1 = MFMA32(vf3, f1.v, o1);
      __builtin_amdgcn_s_setprio(0);
    }
    __syncthreads();
  }
  lsum += __shfl_xor(lsum, 32);
  float rl = 1.0f / lsum;
  int b = bh >> 3, h = bh & 7;
  unsigned short* aorow = ao + ((size_t)(b * 1024 + q0 + lq)) * 512 + h * 64;
  #pragma unroll
  for (int dt2 = 0; dt2 < 2; ++dt2) {
    #pragma unroll
    for (int g = 0; g < 4; ++g) {
      ushort4 pk;
      float v0 = (dt2 ? o1[4 * g + 0] : o0[4 * g + 0]) * rl;
      float v1 = (dt2 ? o1[4 * g + 1] : o0[4 * g + 1]) * rl;
      float v2 = (dt2 ? o1[4 * g + 2] : o0[4 * g + 2]) * rl;
      float v3 = (dt2 ? o1[4 * g + 3] : o0[4 * g + 3]) * rl;
      pk.x = f2bf(v0); pk.y = f2bf(v1); pk.z = f2bf(v2); pk.w = f2bf(v3);
      *(ushort4*)(aorow + dt2 * 32 + 8 * g + 4 * half) = pk;
    }
  }
}

// ---- kernel 6: output GEMM + bias, 8 waves (64x32/wave) (r12) -------------
__global__ __launch_bounds__(512, 6) void k_out(const unsigned short* __restrict__ ao,
                                                const unsigned short* __restrict__ wot,
                                                const float* __restrict__ b_out,
                                                float* __restrict__ out) {
  __shared__ unsigned short As[3][128 * 32];
  __shared__ unsigned short Bs[3][128 * 32];
  int tid = threadIdx.x;
  int wid = tid >> 6, lane = tid & 63;
  int bm = blockIdx.x & 63, bn = blockIdx.x >> 6;   // 64 x 4
  int r0 = bm * 128, c0 = bn * 128;
  int lr = lane & 15, lk = (lane >> 4) * 8;
  int wr = (wid >> 2) * 64, wc = (wid & 3) * 32;
  int srow = tid >> 2, scol = (tid & 3) * 8;
  const unsigned short* gA = ao  + (size_t)(r0 + srow) * 512 + scol;
  const unsigned short* gB = wot + (size_t)(c0 + srow) * 512 + scol;
  int ldsoff = tid * 8;

  f32x4 acc[4][2];
  #pragma unroll
  for (int mi = 0; mi < 4; ++mi)
    #pragma unroll
    for (int ni = 0; ni < 2; ++ni)
      acc[mi][ni] = (f32x4){0.f, 0.f, 0.f, 0.f};

  GLD16(gA,      &As[0][ldsoff]);
  GLD16(gB,      &Bs[0][ldsoff]);
  GLD16(gA + 32, &As[1][ldsoff]);
  GLD16(gB + 32, &Bs[1][ldsoff]);

  int cur = 0, pre = 2;
  for (int t = 0; t < 16; ++t) {
    if (t < 15) asm volatile("s_waitcnt vmcnt(2)" ::: "memory");
    else        asm volatile("s_waitcnt vmcnt(0)" ::: "memory");
    __builtin_amdgcn_s_barrier();
    if (t < 14) {
      int k2 = (t + 2) * 32;
      GLD16(gA + k2, &As[pre][ldsoff]);
      GLD16(gB + k2, &Bs[pre][ldsoff]);
    }
    bf16x8 af[4], bfr[2];
    #pragma unroll
    for (int mi = 0; mi < 4; ++mi)
      af[mi] = *(const bf16x8*)&As[cur][(wr + mi * 16 + lr) * 32 + lk];
    #pragma unroll
    for (int ni = 0; ni < 2; ++ni)
      bfr[ni] = *(const bf16x8*)&Bs[cur][(wc + ni * 16 + lr) * 32 + lk];
    __builtin_amdgcn_s_setprio(1);
    #pragma unroll
    for (int mi = 0; mi < 4; ++mi)
      #pragma unroll
      for (int ni = 0; ni < 2; ++ni)
        acc[mi][ni] = MFMA16(af[mi], bfr[ni], acc[mi][ni]);
    __builtin_amdgcn_s_setprio(0);
    cur = (cur == 2) ? 0 : cur + 1;
    pre = (pre == 2) ? 0 : pre + 1;
  }

  #pragma unroll
  for (int ni = 0; ni < 2; ++ni) {
    int col = c0 + wc + ni * 16 + lr;
    float bias = b_out[col];
    #pragma unroll
    for (int mi = 0; mi < 4; ++mi)
      #pragma unroll
      for (int reg = 0; reg < 4; ++reg) {
        int row = r0 + wr + mi * 16 + (lane >> 4) * 4 + reg;
        out[(size_t)row * 512 + col] = acc[mi][ni][reg] + bias;
      }
  }
}

// ---------------------------------------------------------------------------
extern "C" void kernel_launch(void* const* d_in, const int* in_sizes, int n_in,
                              void* d_out, int out_size, void* d_ws, size_t ws_size,
                              hipStream_t stream) {
  const float* img       = (const float*)d_in[0];
  const float* tab       = (const float*)d_in[1];
  const float* w_qkv     = (const float*)d_in[2];
  const float* w_tab_qkv = (const float*)d_in[3];
  const float* w_out     = (const float*)d_in[4];
  const float* b_out     = (const float*)d_in[5];
  const float* ln_w      = (const float*)d_in[6];
  const float* ln_b      = (const float*)d_in[7];
  char* ws = (char*)d_ws;
  unsigned short* x_bf = (unsigned short*)(ws);             //  8 MiB
  unsigned short* wqt  = (unsigned short*)(ws + 8388608);   //  1.5 MiB
  unsigned short* wot  = (unsigned short*)(ws + 9961472);   //  0.5 MiB
  unsigned short* qh   = (unsigned short*)(ws + 10485760);  //  8 MiB
  unsigned short* kh   = (unsigned short*)(ws + 18874368);  //  8.5 MiB (KPAD)
  unsigned short* vt   = (unsigned short*)(ws + 27787264);  //  8.5 MiB (KPAD)
  unsigned short* ao   = (unsigned short*)(ws + 36700160);  //  8 MiB
  float* out = (float*)d_out;

  hipLaunchKernelGGL(k_pre,  dim3(2432), dim3(256), 0, stream,
                     img, tab, w_qkv, w_tab_qkv, w_out, ln_w, ln_b,
                     x_bf, wqt, wot, kh, vt);
  hipLaunchKernelGGL(k_qkv,  dim3(768),  dim3(512), 0, stream, x_bf, wqt, qh, kh, vt);
  hipLaunchKernelGGL(k_attn, dim3(256),  dim3(512), 0, stream, qh, kh, vt, ao);
  hipLaunchKernelGGL(k_out,  dim3(256),  dim3(512), 0, stream, ao, wot, b_out, out);
}

// Round 16
// 81.218 us; speedup vs baseline: 1.2850x; 1.0126x over previous
//
#include <hip/hip_runtime.h>

// ---------------------------------------------------------------------------
// Attention_43868795961547: LN -> QKV -> MHA(1025 keys) -> proj
// b=8, n=1024, dim=512, heads=8, dh=64. bf16 MFMA, f32 accum.
// Round 16: single change vs r15 (82.24us best): k_out -> 128x64 tiles,
// 512 blocks = 2 blocks/CU (r14's k_out, attributed alone this time).
// k_pre/k_qkv/k_attn byte-identical to round 15.
// ---------------------------------------------------------------------------

typedef __attribute__((ext_vector_type(4))) float f32x4;
typedef __attribute__((ext_vector_type(16))) float f32x16;
typedef __attribute__((ext_vector_type(8))) short bf16x8;
typedef __attribute__((ext_vector_type(8))) unsigned short u16x8;

#define MFMA16(a, b, c) __builtin_amdgcn_mfma_f32_16x16x32_bf16(a, b, c, 0, 0, 0)
#define MFMA32(a, b, c) __builtin_amdgcn_mfma_f32_32x32x16_bf16(a, b, c, 0, 0, 0)

#define GLD16(gsrc, ldst)                                                     \
  __builtin_amdgcn_global_load_lds(                                           \
      (const __attribute__((address_space(1))) void*)(gsrc),                  \
      (__attribute__((address_space(3))) void*)(ldst), 16, 0, 0)

#define KPAD 1088   // keys padded: 17 tiles of 64

// Q pre-scale: dots*0.125 in exp2-domain => fold 0.125*log2(e) into Q.
#define QSCALE 0.18033688011112042f

__device__ __forceinline__ unsigned short f2bf(float f) {
  union { float f; unsigned int u; } c; c.f = f;
  unsigned int u = c.u;
  u += 0x7fffu + ((u >> 16) & 1u);   // RNE
  return (unsigned short)(u >> 16);
}

__device__ __forceinline__ unsigned int cvtpk_bf16(float lo, float hi) {
  unsigned int r;
  asm("v_cvt_pk_bf16_f32 %0, %1, %2" : "=v"(r) : "v"(lo), "v"(hi));
  return r;
}

// ---- kernel 1: fused pre-pass --------------------------------------------
__global__ __launch_bounds__(256) void k_pre(const float* __restrict__ img,
                                             const float* __restrict__ tab,
                                             const float* __restrict__ w_qkv,
                                             const float* __restrict__ w_tab,
                                             const float* __restrict__ w_out,
                                             const float* __restrict__ ln_w,
                                             const float* __restrict__ ln_b,
                                             unsigned short* __restrict__ x_bf,
                                             unsigned short* __restrict__ wqt,
                                             unsigned short* __restrict__ wot,
                                             unsigned short* __restrict__ kh,
                                             unsigned short* __restrict__ vt) {
  int blk = blockIdx.x, tid = threadIdx.x;
  if (blk < 256) {
    __shared__ unsigned short tbuf[64][68];
    const float* src;
    unsigned short* dst;
    int k0, n0, ldin;
    if (blk < 192) {
      int ti = blk / 24, tj = blk % 24;
      k0 = ti * 64; n0 = tj * 64; ldin = 1536;
      src = w_qkv; dst = wqt;
    } else {
      int g = blk - 192;
      int ti = g >> 3, tj = g & 7;
      k0 = ti * 64; n0 = tj * 64; ldin = 512;
      src = w_out; dst = wot;
    }
    int rr = tid >> 4, c4 = (tid & 15) * 4;
    #pragma unroll
    for (int i = 0; i < 4; ++i) {
      int r = i * 16 + rr;
      float4 v = *(const float4*)(src + (size_t)(k0 + r) * ldin + n0 + c4);
      tbuf[c4 + 0][r] = f2bf(v.x);
      tbuf[c4 + 1][r] = f2bf(v.y);
      tbuf[c4 + 2][r] = f2bf(v.z);
      tbuf[c4 + 3][r] = f2bf(v.w);
    }
    __syncthreads();
    #pragma unroll
    for (int i = 0; i < 4; ++i) {
      int r = i * 16 + rr;
      ushort4 w = *(const ushort4*)&tbuf[r][c4];
      *(ushort4*)(dst + (size_t)(n0 + r) * 512 + k0 + c4) = w;
    }
  } else if (blk < 2304) {
    int wid = tid >> 6, lane = tid & 63;
    int row = (blk - 256) * 4 + wid;
    const float* src = img + (size_t)row * 512;
    float4 v0 = *(const float4*)(src + lane * 8);
    float4 v1 = *(const float4*)(src + lane * 8 + 4);
    float x[8] = {v0.x, v0.y, v0.z, v0.w, v1.x, v1.y, v1.z, v1.w};
    float s = 0.f, sq = 0.f;
    #pragma unroll
    for (int j = 0; j < 8; ++j) { s += x[j]; sq += x[j] * x[j]; }
    #pragma unroll
    for (int off = 32; off >= 1; off >>= 1) {
      s  += __shfl_xor(s, off);
      sq += __shfl_xor(sq, off);
    }
    float mean = s * (1.0f / 512.0f);
    float var  = sq * (1.0f / 512.0f) - mean * mean;
    float rs = rsqrtf(var + 1e-5f);
    float4 w0 = *(const float4*)(ln_w + lane * 8);
    float4 w1 = *(const float4*)(ln_w + lane * 8 + 4);
    float4 b0 = *(const float4*)(ln_b + lane * 8);
    float4 b1 = *(const float4*)(ln_b + lane * 8 + 4);
    float w[8] = {w0.x, w0.y, w0.z, w0.w, w1.x, w1.y, w1.z, w1.w};
    float bb[8] = {b0.x, b0.y, b0.z, b0.w, b1.x, b1.y, b1.z, b1.w};
    bf16x8 o;
    #pragma unroll
    for (int j = 0; j < 8; ++j)
      o[j] = (short)f2bf((x[j] - mean) * rs * w[j] + bb[j]);
    *(bf16x8*)(x_bf + (size_t)row * 512 + lane * 8) = o;
  } else {
    __shared__ float tl[512];
    __shared__ float red[4][64];
    __shared__ float ws_[4], wq_[4];
    int blk2 = blk - 2304;           // 128 blocks
    int b = blk2 >> 4, chunk = blk2 & 15;
    int t = tid;
    int lane = t & 63, wid = t >> 6;
    int cl = t & 63;
    int ks = t >> 6;
    int col = chunk * 64 + cl;

    {
      int h = chunk & 7;
      int bh = b * 8 + h;
      u16x8 z = (u16x8)(0);
      if (chunk < 8) {
        unsigned short* base = kh + ((size_t)bh * KPAD + 1024) * 64;
        #pragma unroll
        for (int i = 0; i < 2; ++i)
          *(u16x8*)(base + (t + i * 256) * 8) = z;
      } else {
        #pragma unroll
        for (int i = 0; i < 2; ++i) {
          int idx = t + i * 256;
          int d = idx >> 3, ch = idx & 7;
          *(u16x8*)(vt + ((size_t)bh * 64 + d) * KPAD + 1024 + ch * 8) = z;
        }
      }
    }

    float2 tv = *(const float2*)(tab + (size_t)b * 512 + t * 2);
    float s_ = tv.x + tv.y, q_ = tv.x * tv.x + tv.y * tv.y;
    #pragma unroll
    for (int off = 32; off >= 1; off >>= 1) {
      s_ += __shfl_xor(s_, off);
      q_ += __shfl_xor(q_, off);
    }
    if (lane == 0) { ws_[wid] = s_; wq_[wid] = q_; }
    __syncthreads();
    float S = ws_[0] + ws_[1] + ws_[2] + ws_[3];
    float Qq = wq_[0] + wq_[1] + wq_[2] + wq_[3];
    float mean = S * (1.0f / 512.0f);
    float var = Qq * (1.0f / 512.0f) - mean * mean;
    float rs = rsqrtf(var + 1e-5f);
    tl[t * 2 + 0] = (tv.x - mean) * rs * ln_w[t * 2 + 0] + ln_b[t * 2 + 0];
    tl[t * 2 + 1] = (tv.y - mean) * rs * ln_w[t * 2 + 1] + ln_b[t * 2 + 1];
    __syncthreads();

    const float* wp = w_tab + 512 + col + (size_t)(ks * 128) * 1536;
    float s = 0.f;
    #pragma unroll 8
    for (int k = 0; k < 128; ++k)
      s += tl[ks * 128 + k] * wp[(size_t)k * 1536];
    red[ks][cl] = s;
    __syncthreads();
    if (ks == 0) {
      float v = red[0][cl] + red[1][cl] + red[2][cl] + red[3][cl];
      int part = col >> 9, hd = col & 511, h = hd >> 6, d = hd & 63;
      int bh = b * 8 + h;
      unsigned short hv = f2bf(v);
      if (part == 0) kh[((size_t)bh * KPAD + 1024) * 64 + d] = hv;
      else           vt[((size_t)bh * 64 + d) * KPAD + 1024] = hv;
    }
  }
}

// ---- kernel 4: QKV GEMM, 128x128 tile, BK=64, XOR-swizzled, vmcnt(4) ------
__global__ __launch_bounds__(512, 4) void k_qkv(const unsigned short* __restrict__ x_bf,
                                                const unsigned short* __restrict__ wqt,
                                                unsigned short* __restrict__ qh,
                                                unsigned short* __restrict__ kh,
                                                unsigned short* __restrict__ vt) {
  __shared__ unsigned short As[2][128 * 64];
  __shared__ unsigned short Bs[2][128 * 64];
  int tid = threadIdx.x;                    // 0..511
  int wid = tid >> 6, lane = tid & 63;
  int bm = blockIdx.x & 63, bn = blockIdx.x >> 6;   // 64 x 12
  int r0 = bm * 128, c0 = bn * 128;
  int lr = lane & 15, hc = lane >> 4;       // fragment row / k-chunk (0..3)
  int wr = (wid >> 2) * 64, wc = (wid & 3) * 32;    // 2M x 4N wave grid

  int srow[2], sc[2];
  #pragma unroll
  for (int i = 0; i < 2; ++i) {
    int id = i * 512 + tid;
    srow[i] = id >> 3;
    sc[i] = (id & 7) ^ (srow[i] & 7);
  }

  f32x4 acc[4][2];
  #pragma unroll
  for (int mi = 0; mi < 4; ++mi)
    #pragma unroll
    for (int ni = 0; ni < 2; ++ni)
      acc[mi][ni] = (f32x4){0.f, 0.f, 0.f, 0.f};

  #define STAGE_QKV(kt, buf)                                                   \
    do {                                                                       \
      int kb = (kt) * 64;                                                      \
      _Pragma("unroll")                                                        \
      for (int i = 0; i < 2; ++i)                                              \
        GLD16(x_bf + (size_t)(r0 + srow[i]) * 512 + kb + sc[i] * 8,            \
              &As[buf][(i * 512 + tid) * 8]);                                  \
      _Pragma("unroll")                                                        \
      for (int i = 0; i < 2; ++i)                                              \
        GLD16(wqt + (size_t)(c0 + srow[i]) * 512 + kb + sc[i] * 8,             \
              &Bs[buf][(i * 512 + tid) * 8]);                                  \
    } while (0)

  STAGE_QKV(0, 0);
  STAGE_QKV(1, 1);

  for (int t = 0; t < 8; ++t) {
    int cur = t & 1;
    if (t < 7) asm volatile("s_waitcnt vmcnt(4)" ::: "memory");
    else       asm volatile("s_waitcnt vmcnt(0)" ::: "memory");
    __builtin_amdgcn_s_barrier();           // tile t resident block-wide
    __builtin_amdgcn_sched_barrier(0);
    #pragma unroll
    for (int kk = 0; kk < 2; ++kk) {
      bf16x8 af[4], bfr[2];
      #pragma unroll
      for (int mi = 0; mi < 4; ++mi) {
        int row = wr + mi * 16 + lr;
        int q = (kk * 4 + hc) ^ (row & 7);
        af[mi] = *(const bf16x8*)&As[cur][row * 64 + q * 8];
      }
      #pragma unroll
      for (int ni = 0; ni < 2; ++ni) {
        int row = wc + ni * 16 + lr;
        int q = (kk * 4 + hc) ^ (row & 7);
        bfr[ni] = *(const bf16x8*)&Bs[cur][row * 64 + q * 8];
      }
      __builtin_amdgcn_s_setprio(1);
      #pragma unroll
      for (int mi = 0; mi < 4; ++mi)
        #pragma unroll
        for (int ni = 0; ni < 2; ++ni)
          acc[mi][ni] = MFMA16(af[mi], bfr[ni], acc[mi][ni]);
      __builtin_amdgcn_s_setprio(0);
    }
    __builtin_amdgcn_s_barrier();           // all waves done reading buf[cur]
    __builtin_amdgcn_sched_barrier(0);
    if (t < 6) STAGE_QKV(t + 2, cur);
  }
  #undef STAGE_QKV

  #pragma unroll
  for (int ni = 0; ni < 2; ++ni) {
    int col0 = c0 + wc + ni * 16;
    int which = col0 >> 9;
    int hh = (col0 & 511) >> 6;
    int d = (col0 & 63) + lr;
    #pragma unroll
    for (int mi = 0; mi < 4; ++mi)
      #pragma unroll
      for (int reg = 0; reg < 4; ++reg) {
        int row = r0 + wr + mi * 16 + (lane >> 4) * 4 + reg;
        int b = row >> 10, n = row & 1023;
        int bh = b * 8 + hh;
        float v = acc[mi][ni][reg];
        if (which == 0) {
          qh[((size_t)bh * 1024 + n) * 64 + d] = f2bf(v * QSCALE);
        } else if (which == 1) {
          kh[((size_t)bh * KPAD + n) * 64 + d] = f2bf(v);
        } else {
          vt[((size_t)bh * 64 + d) * KPAD + n] = f2bf(v);
        }
      }
  }
}

// ---- kernel 5: flash attention, 8-wave block + LDS-staged K/V (r12) -------
__global__ __launch_bounds__(512, 4) void k_attn(const unsigned short* __restrict__ qh,
                                                 const unsigned short* __restrict__ kh,
                                                 const unsigned short* __restrict__ vt,
                                                 unsigned short* __restrict__ ao) {
  __shared__ __align__(16) unsigned short Ks[2][4096];  // [64 key][64 d] swz
  __shared__ __align__(16) unsigned short Vs[2][4096];  // [64 d][64 key] swz
  int tid = threadIdx.x;
  int wid = tid >> 6, lane = tid & 63;
  int bid = blockIdx.x;
  int swz = ((bid & 7) << 5) | (bid >> 3);   // bijective; 8 bh per XCD
  int bh = swz >> 2;
  int q0 = (swz & 3) * 256 + wid * 32;
  int lq = lane & 31, half = lane >> 5;

  const unsigned short* Q  = qh + (size_t)bh * 1024 * 64;
  const unsigned short* Kg = kh + (size_t)bh * KPAD * 64;
  const unsigned short* Vg = vt + (size_t)bh * 64 * KPAD;

  int xr = tid >> 3;
  int xc = (tid & 7) ^ (xr & 7);
  const unsigned short* kg_src = Kg + xr * 64 + xc * 8;
  const unsigned short* vg_src = Vg + (size_t)xr * KPAD + xc * 8;
  unsigned short* kdstA = &Ks[0][wid * 512];
  unsigned short* kdstB = &Ks[1][wid * 512];
  unsigned short* vdstA = &Vs[0][wid * 512];
  unsigned short* vdstB = &Vs[1][wid * 512];

  bf16x8 qf[4];
  const unsigned short* qlane = Q + (size_t)(q0 + lq) * 64 + half * 8;
  #pragma unroll
  for (int dt = 0; dt < 4; ++dt)
    qf[dt] = *(const bf16x8*)(qlane + dt * 16);

  f32x16 o0 = (f32x16)(0.0f), o1 = (f32x16)(0.0f);
  float m = -1e30f, lsum = 0.f;

  GLD16(kg_src, kdstA);
  GLD16(vg_src, vdstA);
  __syncthreads();

  for (int kt = 0; kt < 17; ++kt) {
    int cur = kt & 1;
    if (kt < 16) {
      GLD16(kg_src + (kt + 1) * 4096, cur ? kdstA : kdstB);
      GLD16(vg_src + (kt + 1) * 64,   cur ? vdstA : vdstB);
    }
    const unsigned short* Kb = Ks[cur];
    const unsigned short* Vb = Vs[cur];
    #pragma unroll
    for (int sub = 0; sub < 2; ++sub) {
      int krow = sub * 32 + lq;
      bf16x8 kf[4];
      #pragma unroll
      for (int dt = 0; dt < 4; ++dt) {
        int ch = (half + dt * 2) ^ (krow & 7);
        kf[dt] = *(const bf16x8*)&Kb[krow * 64 + ch * 8];
      }
      f32x16 s = (f32x16)(0.0f);
      __builtin_amdgcn_s_setprio(1);
      #pragma unroll
      for (int dt = 0; dt < 4; ++dt)
        s = MFMA32(kf[dt], qf[dt], s);
      __builtin_amdgcn_s_setprio(0);
      if (kt == 16) {
        if (sub == 0) {
          #pragma unroll
          for (int reg = 0; reg < 16; ++reg) {
            if (reg == 0) { if (half) s[0] = -1e30f; }
            else s[reg] = -1e30f;
          }
        } else {
          #pragma unroll
          for (int reg = 0; reg < 16; ++reg) s[reg] = -1e30f;
        }
      }
      float pmax = s[0];
      #pragma unroll
      for (int reg = 1; reg < 16; ++reg) pmax = fmaxf(pmax, s[reg]);
      pmax = fmaxf(pmax, __shfl_xor(pmax, 32));
      if (!__all(pmax <= m + 8.0f)) {
        float mnew = fmaxf(m, pmax);
        float al = __builtin_amdgcn_exp2f(m - mnew);
        lsum *= al;
        #pragma unroll
        for (int reg = 0; reg < 16; ++reg) { o0[reg] *= al; o1[reg] *= al; }
        m = mnew;
      }
      float p[16];
      float ls = 0.f;
      #pragma unroll
      for (int reg = 0; reg < 16; ++reg) {
        p[reg] = __builtin_amdgcn_exp2f(s[reg] - m);
        ls += p[reg];
      }
      lsum += ls;
      unsigned int c0x0 = cvtpk_bf16(p[0],  p[1]);
      unsigned int c0x1 = cvtpk_bf16(p[2],  p[3]);
      unsigned int c0y0 = cvtpk_bf16(p[4],  p[5]);
      unsigned int c0y1 = cvtpk_bf16(p[6],  p[7]);
      unsigned int c1x0 = cvtpk_bf16(p[8],  p[9]);
      unsigned int c1x1 = cvtpk_bf16(p[10], p[11]);
      unsigned int c1y0 = cvtpk_bf16(p[12], p[13]);
      unsigned int c1y1 = cvtpk_bf16(p[14], p[15]);
      asm volatile("v_permlane32_swap_b32 %0, %1" : "+v"(c0x0), "+v"(c0y0));
      asm volatile("v_permlane32_swap_b32 %0, %1" : "+v"(c0x1), "+v"(c0y1));
      asm volatile("v_permlane32_swap_b32 %0, %1" : "+v"(c1x0), "+v"(c1y0));
      asm volatile("v_permlane32_swap_b32 %0, %1" : "+v"(c1x1), "+v"(c1y1));
      union { unsigned int w[4]; bf16x8 v; } f0, f1;
      f0.w[0] = c0x0; f0.w[1] = c0x1; f0.w[2] = c0y0; f0.w[3] = c0y1;
      f1.w[0] = c1x0; f1.w[1] = c1x1; f1.w[2] = c1y0; f1.w[3] = c1y1;
      int vr0 = lq, vr1 = lq + 32;
      int cb = sub * 4 + half;
      bf16x8 vf0 = *(const bf16x8*)&Vb[vr0 * 64 + ((cb + 0) ^ (vr0 & 7)) * 8];
      bf16x8 vf1 = *(const bf16x8*)&Vb[vr0 * 64 + ((cb + 2) ^ (vr0 & 7)) * 8];
      bf16x8 vf2 = *(const bf16x8*)&Vb[vr1 * 64 + ((cb + 0) ^ (vr1 & 7)) * 8];
      bf16x8 vf3 = *(const bf16x8*)&Vb[vr1 * 64 + ((cb + 2) ^ (vr1 & 7)) * 8];
      __builtin_amdgcn_s_setprio(1);
      o0 = MFMA32(vf0, f0.v, o0);
      o0 = MFMA32(vf1, f1.v, o0);
      o1 = MFMA32(vf2, f0.v, o1);
      o1 = MFMA32(vf3, f1.v, o1);
      __builtin_amdgcn_s_setprio(0);
    }
    __syncthreads();
  }
  lsum += __shfl_xor(lsum, 32);
  float rl = 1.0f / lsum;
  int b = bh >> 3, h = bh & 7;
  unsigned short* aorow = ao + ((size_t)(b * 1024 + q0 + lq)) * 512 + h * 64;
  #pragma unroll
  for (int dt2 = 0; dt2 < 2; ++dt2) {
    #pragma unroll
    for (int g = 0; g < 4; ++g) {
      ushort4 pk;
      float v0 = (dt2 ? o1[4 * g + 0] : o0[4 * g + 0]) * rl;
      float v1 = (dt2 ? o1[4 * g + 1] : o0[4 * g + 1]) * rl;
      float v2 = (dt2 ? o1[4 * g + 2] : o0[4 * g + 2]) * rl;
      float v3 = (dt2 ? o1[4 * g + 3] : o0[4 * g + 3]) * rl;
      pk.x = f2bf(v0); pk.y = f2bf(v1); pk.z = f2bf(v2); pk.w = f2bf(v3);
      *(ushort4*)(aorow + dt2 * 32 + 8 * g + 4 * half) = pk;
    }
  }
}

// ---- kernel 6: output GEMM + bias, 4-wave blocks (128x64 tile) ------------
// 512 blocks (64 x 8) x 256 thr; wave tile 64x32 (2M x 2N). 3-ring LDS,
// counted vmcnt(3) (per-thread 3 loads/tile: 2 A + 1 B).
__global__ __launch_bounds__(256, 4) void k_out(const unsigned short* __restrict__ ao,
                                                const unsigned short* __restrict__ wot,
                                                const float* __restrict__ b_out,
                                                float* __restrict__ out) {
  __shared__ unsigned short As[3][128 * 32];
  __shared__ unsigned short Bs[3][64 * 32];
  int tid = threadIdx.x;
  int wid = tid >> 6, lane = tid & 63;
  int bm = blockIdx.x & 63, bn = blockIdx.x >> 6;   // 64 x 8
  int r0 = bm * 128, c0 = bn * 64;
  int lr = lane & 15, lk = (lane >> 4) * 8;
  int wr = (wid >> 1) * 64, wc = (wid & 1) * 32;    // 2M x 2N
  int srowA0 = tid >> 2, srowA1 = 64 + (tid >> 2), scol = (tid & 3) * 8;
  const unsigned short* gA0 = ao  + (size_t)(r0 + srowA0) * 512 + scol;
  const unsigned short* gA1 = ao  + (size_t)(r0 + srowA1) * 512 + scol;
  const unsigned short* gB  = wot + (size_t)(c0 + srowA0) * 512 + scol;  // rows 0..63
  int offA0 = tid * 8, offA1 = 2048 + tid * 8, offB = tid * 8;

  f32x4 acc[4][2];
  #pragma unroll
  for (int mi = 0; mi < 4; ++mi)
    #pragma unroll
    for (int ni = 0; ni < 2; ++ni)
      acc[mi][ni] = (f32x4){0.f, 0.f, 0.f, 0.f};

  GLD16(gA0,      &As[0][offA0]);
  GLD16(gA1,      &As[0][offA1]);
  GLD16(gB,       &Bs[0][offB]);
  GLD16(gA0 + 32, &As[1][offA0]);
  GLD16(gA1 + 32, &As[1][offA1]);
  GLD16(gB  + 32, &Bs[1][offB]);

  int cur = 0, pre = 2;
  for (int t = 0; t < 16; ++t) {
    if (t < 15) asm volatile("s_waitcnt vmcnt(3)" ::: "memory");
    else        asm volatile("s_waitcnt vmcnt(0)" ::: "memory");
    __builtin_amdgcn_s_barrier();
    if (t < 14) {
      int k2 = (t + 2) * 32;
      GLD16(gA0 + k2, &As[pre][offA0]);
      GLD16(gA1 + k2, &As[pre][offA1]);
      GLD16(gB  + k2, &Bs[pre][offB]);
    }
    bf16x8 af[4], bfr[2];
    #pragma unroll
    for (int mi = 0; mi < 4; ++mi)
      af[mi] = *(const bf16x8*)&As[cur][(wr + mi * 16 + lr) * 32 + lk];
    #pragma unroll
    for (int ni = 0; ni < 2; ++ni)
      bfr[ni] = *(const bf16x8*)&Bs[cur][(wc + ni * 16 + lr) * 32 + lk];
    __builtin_amdgcn_s_setprio(1);
    #pragma unroll
    for (int mi = 0; mi < 4; ++mi)
      #pragma unroll
      for (int ni = 0; ni < 2; ++ni)
        acc[mi][ni] = MFMA16(af[mi], bfr[ni], acc[mi][ni]);
    __builtin_amdgcn_s_setprio(0);
    cur = (cur == 2) ? 0 : cur + 1;
    pre = (pre == 2) ? 0 : pre + 1;
  }

  #pragma unroll
  for (int ni = 0; ni < 2; ++ni) {
    int col = c0 + wc + ni * 16 + lr;
    float bias = b_out[col];
    #pragma unroll
    for (int mi = 0; mi < 4; ++mi)
      #pragma unroll
      for (int reg = 0; reg < 4; ++reg) {
        int row = r0 + wr + mi * 16 + (lane >> 4) * 4 + reg;
        out[(size_t)row * 512 + col] = acc[mi][ni][reg] + bias;
      }
  }
}

// ---------------------------------------------------------------------------
extern "C" void kernel_launch(void* const* d_in, const int* in_sizes, int n_in,
                              void* d_out, int out_size, void* d_ws, size_t ws_size,
                              hipStream_t stream) {
  const float* img       = (const float*)d_in[0];
  const float* tab       = (const float*)d_in[1];
  const float* w_qkv     = (const float*)d_in[2];
  const float* w_tab_qkv = (const float*)d_in[3];
  const float* w_out     = (const float*)d_in[4];
  const float* b_out     = (const float*)d_in[5];
  const float* ln_w      = (const float*)d_in[6];
  const float* ln_b      = (const float*)d_in[7];
  char* ws = (char*)d_ws;
  unsigned short* x_bf = (unsigned short*)(ws);             //  8 MiB
  unsigned short* wqt  = (unsigned short*)(ws + 8388608);   //  1.5 MiB
  unsigned short* wot  = (unsigned short*)(ws + 9961472);   //  0.5 MiB
  unsigned short* qh   = (unsigned short*)(ws + 10485760);  //  8 MiB
  unsigned short* kh   = (unsigned short*)(ws + 18874368);  //  8.5 MiB (KPAD)
  unsigned short* vt   = (unsigned short*)(ws + 27787264);  //  8.5 MiB (KPAD)
  unsigned short* ao   = (unsigned short*)(ws + 36700160);  //  8 MiB
  float* out = (float*)d_out;

  hipLaunchKernelGGL(k_pre,  dim3(2432), dim3(256), 0, stream,
                     img, tab, w_qkv, w_tab_qkv, w_out, ln_w, ln_b,
                     x_bf, wqt, wot, kh, vt);
  hipLaunchKernelGGL(k_qkv,  dim3(768),  dim3(512), 0, stream, x_bf, wqt, qh, kh, vt);
  hipLaunchKernelGGL(k_attn, dim3(256),  dim3(512), 0, stream, qh, kh, vt, ao);
  hipLaunchKernelGGL(k_out,  dim3(512),  dim3(256), 0, stream, ao, wot, b_out, out);
}

// Round 17
// 77.346 us; speedup vs baseline: 1.3493x; 1.0501x over previous
//
#include <hip/hip_runtime.h>

// ---------------------------------------------------------------------------
// Attention_43868795961547: LN -> QKV -> MHA(1025 keys) -> proj
// b=8, n=1024, dim=512, heads=8, dh=64. bf16 MFMA, f32 accum.
// Round 17: single change vs r16 (81.2us best): k_qkv V-panel epilogue
// (bn>=8 blocks) -> LDS transpose (reuse retired As as 128x128 scratch) +
// coalesced 16B stores along keys, replacing 2176B-strided 2B scatter.
// k_pre/k_attn/k_out byte-identical to round 16.
// ---------------------------------------------------------------------------

typedef __attribute__((ext_vector_type(4))) float f32x4;
typedef __attribute__((ext_vector_type(16))) float f32x16;
typedef __attribute__((ext_vector_type(8))) short bf16x8;
typedef __attribute__((ext_vector_type(8))) unsigned short u16x8;

#define MFMA16(a, b, c) __builtin_amdgcn_mfma_f32_16x16x32_bf16(a, b, c, 0, 0, 0)
#define MFMA32(a, b, c) __builtin_amdgcn_mfma_f32_32x32x16_bf16(a, b, c, 0, 0, 0)

#define GLD16(gsrc, ldst)                                                     \
  __builtin_amdgcn_global_load_lds(                                           \
      (const __attribute__((address_space(1))) void*)(gsrc),                  \
      (__attribute__((address_space(3))) void*)(ldst), 16, 0, 0)

#define KPAD 1088   // keys padded: 17 tiles of 64

// Q pre-scale: dots*0.125 in exp2-domain => fold 0.125*log2(e) into Q.
#define QSCALE 0.18033688011112042f

__device__ __forceinline__ unsigned short f2bf(float f) {
  union { float f; unsigned int u; } c; c.f = f;
  unsigned int u = c.u;
  u += 0x7fffu + ((u >> 16) & 1u);   // RNE
  return (unsigned short)(u >> 16);
}

__device__ __forceinline__ unsigned int cvtpk_bf16(float lo, float hi) {
  unsigned int r;
  asm("v_cvt_pk_bf16_f32 %0, %1, %2" : "=v"(r) : "v"(lo), "v"(hi));
  return r;
}

// ---- kernel 1: fused pre-pass --------------------------------------------
__global__ __launch_bounds__(256) void k_pre(const float* __restrict__ img,
                                             const float* __restrict__ tab,
                                             const float* __restrict__ w_qkv,
                                             const float* __restrict__ w_tab,
                                             const float* __restrict__ w_out,
                                             const float* __restrict__ ln_w,
                                             const float* __restrict__ ln_b,
                                             unsigned short* __restrict__ x_bf,
                                             unsigned short* __restrict__ wqt,
                                             unsigned short* __restrict__ wot,
                                             unsigned short* __restrict__ kh,
                                             unsigned short* __restrict__ vt) {
  int blk = blockIdx.x, tid = threadIdx.x;
  if (blk < 256) {
    __shared__ unsigned short tbuf[64][68];
    const float* src;
    unsigned short* dst;
    int k0, n0, ldin;
    if (blk < 192) {
      int ti = blk / 24, tj = blk % 24;
      k0 = ti * 64; n0 = tj * 64; ldin = 1536;
      src = w_qkv; dst = wqt;
    } else {
      int g = blk - 192;
      int ti = g >> 3, tj = g & 7;
      k0 = ti * 64; n0 = tj * 64; ldin = 512;
      src = w_out; dst = wot;
    }
    int rr = tid >> 4, c4 = (tid & 15) * 4;
    #pragma unroll
    for (int i = 0; i < 4; ++i) {
      int r = i * 16 + rr;
      float4 v = *(const float4*)(src + (size_t)(k0 + r) * ldin + n0 + c4);
      tbuf[c4 + 0][r] = f2bf(v.x);
      tbuf[c4 + 1][r] = f2bf(v.y);
      tbuf[c4 + 2][r] = f2bf(v.z);
      tbuf[c4 + 3][r] = f2bf(v.w);
    }
    __syncthreads();
    #pragma unroll
    for (int i = 0; i < 4; ++i) {
      int r = i * 16 + rr;
      ushort4 w = *(const ushort4*)&tbuf[r][c4];
      *(ushort4*)(dst + (size_t)(n0 + r) * 512 + k0 + c4) = w;
    }
  } else if (blk < 2304) {
    int wid = tid >> 6, lane = tid & 63;
    int row = (blk - 256) * 4 + wid;
    const float* src = img + (size_t)row * 512;
    float4 v0 = *(const float4*)(src + lane * 8);
    float4 v1 = *(const float4*)(src + lane * 8 + 4);
    float x[8] = {v0.x, v0.y, v0.z, v0.w, v1.x, v1.y, v1.z, v1.w};
    float s = 0.f, sq = 0.f;
    #pragma unroll
    for (int j = 0; j < 8; ++j) { s += x[j]; sq += x[j] * x[j]; }
    #pragma unroll
    for (int off = 32; off >= 1; off >>= 1) {
      s  += __shfl_xor(s, off);
      sq += __shfl_xor(sq, off);
    }
    float mean = s * (1.0f / 512.0f);
    float var  = sq * (1.0f / 512.0f) - mean * mean;
    float rs = rsqrtf(var + 1e-5f);
    float4 w0 = *(const float4*)(ln_w + lane * 8);
    float4 w1 = *(const float4*)(ln_w + lane * 8 + 4);
    float4 b0 = *(const float4*)(ln_b + lane * 8);
    float4 b1 = *(const float4*)(ln_b + lane * 8 + 4);
    float w[8] = {w0.x, w0.y, w0.z, w0.w, w1.x, w1.y, w1.z, w1.w};
    float bb[8] = {b0.x, b0.y, b0.z, b0.w, b1.x, b1.y, b1.z, b1.w};
    bf16x8 o;
    #pragma unroll
    for (int j = 0; j < 8; ++j)
      o[j] = (short)f2bf((x[j] - mean) * rs * w[j] + bb[j]);
    *(bf16x8*)(x_bf + (size_t)row * 512 + lane * 8) = o;
  } else {
    __shared__ float tl[512];
    __shared__ float red[4][64];
    __shared__ float ws_[4], wq_[4];
    int blk2 = blk - 2304;           // 128 blocks
    int b = blk2 >> 4, chunk = blk2 & 15;
    int t = tid;
    int lane = t & 63, wid = t >> 6;
    int cl = t & 63;
    int ks = t >> 6;
    int col = chunk * 64 + cl;

    {
      int h = chunk & 7;
      int bh = b * 8 + h;
      u16x8 z = (u16x8)(0);
      if (chunk < 8) {
        unsigned short* base = kh + ((size_t)bh * KPAD + 1024) * 64;
        #pragma unroll
        for (int i = 0; i < 2; ++i)
          *(u16x8*)(base + (t + i * 256) * 8) = z;
      } else {
        #pragma unroll
        for (int i = 0; i < 2; ++i) {
          int idx = t + i * 256;
          int d = idx >> 3, ch = idx & 7;
          *(u16x8*)(vt + ((size_t)bh * 64 + d) * KPAD + 1024 + ch * 8) = z;
        }
      }
    }

    float2 tv = *(const float2*)(tab + (size_t)b * 512 + t * 2);
    float s_ = tv.x + tv.y, q_ = tv.x * tv.x + tv.y * tv.y;
    #pragma unroll
    for (int off = 32; off >= 1; off >>= 1) {
      s_ += __shfl_xor(s_, off);
      q_ += __shfl_xor(q_, off);
    }
    if (lane == 0) { ws_[wid] = s_; wq_[wid] = q_; }
    __syncthreads();
    float S = ws_[0] + ws_[1] + ws_[2] + ws_[3];
    float Qq = wq_[0] + wq_[1] + wq_[2] + wq_[3];
    float mean = S * (1.0f / 512.0f);
    float var = Qq * (1.0f / 512.0f) - mean * mean;
    float rs = rsqrtf(var + 1e-5f);
    tl[t * 2 + 0] = (tv.x - mean) * rs * ln_w[t * 2 + 0] + ln_b[t * 2 + 0];
    tl[t * 2 + 1] = (tv.y - mean) * rs * ln_w[t * 2 + 1] + ln_b[t * 2 + 1];
    __syncthreads();

    const float* wp = w_tab + 512 + col + (size_t)(ks * 128) * 1536;
    float s = 0.f;
    #pragma unroll 8
    for (int k = 0; k < 128; ++k)
      s += tl[ks * 128 + k] * wp[(size_t)k * 1536];
    red[ks][cl] = s;
    __syncthreads();
    if (ks == 0) {
      float v = red[0][cl] + red[1][cl] + red[2][cl] + red[3][cl];
      int part = col >> 9, hd = col & 511, h = hd >> 6, d = hd & 63;
      int bh = b * 8 + h;
      unsigned short hv = f2bf(v);
      if (part == 0) kh[((size_t)bh * KPAD + 1024) * 64 + d] = hv;
      else           vt[((size_t)bh * 64 + d) * KPAD + 1024] = hv;
    }
  }
}

// ---- kernel 4: QKV GEMM, 128x128 tile, BK=64, XOR-swizzled, vmcnt(4) ------
// V-panel blocks (bn>=8): LDS-transpose epilogue (As reused as scratch).
__global__ __launch_bounds__(512, 4) void k_qkv(const unsigned short* __restrict__ x_bf,
                                                const unsigned short* __restrict__ wqt,
                                                unsigned short* __restrict__ qh,
                                                unsigned short* __restrict__ kh,
                                                unsigned short* __restrict__ vt) {
  __shared__ __align__(16) unsigned short As[2][128 * 64];
  __shared__ __align__(16) unsigned short Bs[2][128 * 64];
  int tid = threadIdx.x;                    // 0..511
  int wid = tid >> 6, lane = tid & 63;
  int bm = blockIdx.x & 63, bn = blockIdx.x >> 6;   // 64 x 12
  int r0 = bm * 128, c0 = bn * 128;
  int lr = lane & 15, hc = lane >> 4;       // fragment row / k-chunk (0..3)
  int wr = (wid >> 2) * 64, wc = (wid & 3) * 32;    // 2M x 4N wave grid

  int srow[2], sc[2];
  #pragma unroll
  for (int i = 0; i < 2; ++i) {
    int id = i * 512 + tid;
    srow[i] = id >> 3;
    sc[i] = (id & 7) ^ (srow[i] & 7);
  }

  f32x4 acc[4][2];
  #pragma unroll
  for (int mi = 0; mi < 4; ++mi)
    #pragma unroll
    for (int ni = 0; ni < 2; ++ni)
      acc[mi][ni] = (f32x4){0.f, 0.f, 0.f, 0.f};

  #define STAGE_QKV(kt, buf)                                                   \
    do {                                                                       \
      int kb = (kt) * 64;                                                      \
      _Pragma("unroll")                                                        \
      for (int i = 0; i < 2; ++i)                                              \
        GLD16(x_bf + (size_t)(r0 + srow[i]) * 512 + kb + sc[i] * 8,            \
              &As[buf][(i * 512 + tid) * 8]);                                  \
      _Pragma("unroll")                                                        \
      for (int i = 0; i < 2; ++i)                                              \
        GLD16(wqt + (size_t)(c0 + srow[i]) * 512 + kb + sc[i] * 8,             \
              &Bs[buf][(i * 512 + tid) * 8]);                                  \
    } while (0)

  STAGE_QKV(0, 0);
  STAGE_QKV(1, 1);

  for (int t = 0; t < 8; ++t) {
    int cur = t & 1;
    if (t < 7) asm volatile("s_waitcnt vmcnt(4)" ::: "memory");
    else       asm volatile("s_waitcnt vmcnt(0)" ::: "memory");
    __builtin_amdgcn_s_barrier();           // tile t resident block-wide
    __builtin_amdgcn_sched_barrier(0);
    #pragma unroll
    for (int kk = 0; kk < 2; ++kk) {
      bf16x8 af[4], bfr[2];
      #pragma unroll
      for (int mi = 0; mi < 4; ++mi) {
        int row = wr + mi * 16 + lr;
        int q = (kk * 4 + hc) ^ (row & 7);
        af[mi] = *(const bf16x8*)&As[cur][row * 64 + q * 8];
      }
      #pragma unroll
      for (int ni = 0; ni < 2; ++ni) {
        int row = wc + ni * 16 + lr;
        int q = (kk * 4 + hc) ^ (row & 7);
        bfr[ni] = *(const bf16x8*)&Bs[cur][row * 64 + q * 8];
      }
      __builtin_amdgcn_s_setprio(1);
      #pragma unroll
      for (int mi = 0; mi < 4; ++mi)
        #pragma unroll
        for (int ni = 0; ni < 2; ++ni)
          acc[mi][ni] = MFMA16(af[mi], bfr[ni], acc[mi][ni]);
      __builtin_amdgcn_s_setprio(0);
    }
    __builtin_amdgcn_s_barrier();           // all waves done reading buf[cur]
    __builtin_amdgcn_sched_barrier(0);
    if (t < 6) STAGE_QKV(t + 2, cur);
  }
  #undef STAGE_QKV

  if (bn < 8) {
    // Q / K panels: row-major per-element stores (consecutive lr -> d)
    #pragma unroll
    for (int ni = 0; ni < 2; ++ni) {
      int col0 = c0 + wc + ni * 16;
      int which = col0 >> 9;
      int hh = (col0 & 511) >> 6;
      int d = (col0 & 63) + lr;
      #pragma unroll
      for (int mi = 0; mi < 4; ++mi)
        #pragma unroll
        for (int reg = 0; reg < 4; ++reg) {
          int row = r0 + wr + mi * 16 + (lane >> 4) * 4 + reg;
          int b = row >> 10, n = row & 1023;
          int bh = b * 8 + hh;
          float v = acc[mi][ni][reg];
          if (which == 0) {
            qh[((size_t)bh * 1024 + n) * 64 + d] = f2bf(v * QSCALE);
          } else {
            kh[((size_t)bh * KPAD + n) * 64 + d] = f2bf(v);
          }
        }
    }
  } else {
    // V panel: transpose via retired As (exactly 128x128 shorts), then
    // coalesced 16B stores along the key dimension.
    unsigned short* scratch = (unsigned short*)As;
    #pragma unroll
    for (int ni = 0; ni < 2; ++ni) {
      int cl = wc + ni * 16 + lr;
      #pragma unroll
      for (int mi = 0; mi < 4; ++mi)
        #pragma unroll
        for (int reg = 0; reg < 4; ++reg) {
          int rl = wr + mi * 16 + (lane >> 4) * 4 + reg;
          scratch[cl * 128 + rl] = f2bf(acc[mi][ni][reg]);
        }
    }
    __syncthreads();
    int b = r0 >> 10, nbase = r0 & 1023;
    int cl = tid >> 2, seg = tid & 3;           // col 0..127, quarter 0..3
    int hh = ((bn - 8) * 128 + cl) >> 6;
    int d = cl & 63;
    int bh = b * 8 + hh;
    unsigned short* dst = vt + ((size_t)bh * 64 + d) * KPAD + nbase + seg * 32;
    const unsigned short* srcp = scratch + cl * 128 + seg * 32;
    #pragma unroll
    for (int j = 0; j < 4; ++j)
      *(u16x8*)(dst + j * 8) = *(const u16x8*)(srcp + j * 8);
  }
}

// ---- kernel 5: flash attention, 8-wave block + LDS-staged K/V (r12) -------
__global__ __launch_bounds__(512, 4) void k_attn(const unsigned short* __restrict__ qh,
                                                 const unsigned short* __restrict__ kh,
                                                 const unsigned short* __restrict__ vt,
                                                 unsigned short* __restrict__ ao) {
  __shared__ __align__(16) unsigned short Ks[2][4096];  // [64 key][64 d] swz
  __shared__ __align__(16) unsigned short Vs[2][4096];  // [64 d][64 key] swz
  int tid = threadIdx.x;
  int wid = tid >> 6, lane = tid & 63;
  int bid = blockIdx.x;
  int swz = ((bid & 7) << 5) | (bid >> 3);   // bijective; 8 bh per XCD
  int bh = swz >> 2;
  int q0 = (swz & 3) * 256 + wid * 32;
  int lq = lane & 31, half = lane >> 5;

  const unsigned short* Q  = qh + (size_t)bh * 1024 * 64;
  const unsigned short* Kg = kh + (size_t)bh * KPAD * 64;
  const unsigned short* Vg = vt + (size_t)bh * 64 * KPAD;

  int xr = tid >> 3;
  int xc = (tid & 7) ^ (xr & 7);
  const unsigned short* kg_src = Kg + xr * 64 + xc * 8;
  const unsigned short* vg_src = Vg + (size_t)xr * KPAD + xc * 8;
  unsigned short* kdstA = &Ks[0][wid * 512];
  unsigned short* kdstB = &Ks[1][wid * 512];
  unsigned short* vdstA = &Vs[0][wid * 512];
  unsigned short* vdstB = &Vs[1][wid * 512];

  bf16x8 qf[4];
  const unsigned short* qlane = Q + (size_t)(q0 + lq) * 64 + half * 8;
  #pragma unroll
  for (int dt = 0; dt < 4; ++dt)
    qf[dt] = *(const bf16x8*)(qlane + dt * 16);

  f32x16 o0 = (f32x16)(0.0f), o1 = (f32x16)(0.0f);
  float m = -1e30f, lsum = 0.f;

  GLD16(kg_src, kdstA);
  GLD16(vg_src, vdstA);
  __syncthreads();

  for (int kt = 0; kt < 17; ++kt) {
    int cur = kt & 1;
    if (kt < 16) {
      GLD16(kg_src + (kt + 1) * 4096, cur ? kdstA : kdstB);
      GLD16(vg_src + (kt + 1) * 64,   cur ? vdstA : vdstB);
    }
    const unsigned short* Kb = Ks[cur];
    const unsigned short* Vb = Vs[cur];
    #pragma unroll
    for (int sub = 0; sub < 2; ++sub) {
      int krow = sub * 32 + lq;
      bf16x8 kf[4];
      #pragma unroll
      for (int dt = 0; dt < 4; ++dt) {
        int ch = (half + dt * 2) ^ (krow & 7);
        kf[dt] = *(const bf16x8*)&Kb[krow * 64 + ch * 8];
      }
      f32x16 s = (f32x16)(0.0f);
      __builtin_amdgcn_s_setprio(1);
      #pragma unroll
      for (int dt = 0; dt < 4; ++dt)
        s = MFMA32(kf[dt], qf[dt], s);
      __builtin_amdgcn_s_setprio(0);
      if (kt == 16) {
        if (sub == 0) {
          #pragma unroll
          for (int reg = 0; reg < 16; ++reg) {
            if (reg == 0) { if (half) s[0] = -1e30f; }
            else s[reg] = -1e30f;
          }
        } else {
          #pragma unroll
          for (int reg = 0; reg < 16; ++reg) s[reg] = -1e30f;
        }
      }
      float pmax = s[0];
      #pragma unroll
      for (int reg = 1; reg < 16; ++reg) pmax = fmaxf(pmax, s[reg]);
      pmax = fmaxf(pmax, __shfl_xor(pmax, 32));
      if (!__all(pmax <= m + 8.0f)) {
        float mnew = fmaxf(m, pmax);
        float al = __builtin_amdgcn_exp2f(m - mnew);
        lsum *= al;
        #pragma unroll
        for (int reg = 0; reg < 16; ++reg) { o0[reg] *= al; o1[reg] *= al; }
        m = mnew;
      }
      float p[16];
      float ls = 0.f;
      #pragma unroll
      for (int reg = 0; reg < 16; ++reg) {
        p[reg] = __builtin_amdgcn_exp2f(s[reg] - m);
        ls += p[reg];
      }
      lsum += ls;
      unsigned int c0x0 = cvtpk_bf16(p[0],  p[1]);
      unsigned int c0x1 = cvtpk_bf16(p[2],  p[3]);
      unsigned int c0y0 = cvtpk_bf16(p[4],  p[5]);
      unsigned int c0y1 = cvtpk_bf16(p[6],  p[7]);
      unsigned int c1x0 = cvtpk_bf16(p[8],  p[9]);
      unsigned int c1x1 = cvtpk_bf16(p[10], p[11]);
      unsigned int c1y0 = cvtpk_bf16(p[12], p[13]);
      unsigned int c1y1 = cvtpk_bf16(p[14], p[15]);
      asm volatile("v_permlane32_swap_b32 %0, %1" : "+v"(c0x0), "+v"(c0y0));
      asm volatile("v_permlane32_swap_b32 %0, %1" : "+v"(c0x1), "+v"(c0y1));
      asm volatile("v_permlane32_swap_b32 %0, %1" : "+v"(c1x0), "+v"(c1y0));
      asm volatile("v_permlane32_swap_b32 %0, %1" : "+v"(c1x1), "+v"(c1y1));
      union { unsigned int w[4]; bf16x8 v; } f0, f1;
      f0.w[0] = c0x0; f0.w[1] = c0x1; f0.w[2] = c0y0; f0.w[3] = c0y1;
      f1.w[0] = c1x0; f1.w[1] = c1x1; f1.w[2] = c1y0; f1.w[3] = c1y1;
      int vr0 = lq, vr1 = lq + 32;
      int cb = sub * 4 + half;
      bf16x8 vf0 = *(const bf16x8*)&Vb[vr0 * 64 + ((cb + 0) ^ (vr0 & 7)) * 8];
      bf16x8 vf1 = *(const bf16x8*)&Vb[vr0 * 64 + ((cb + 2) ^ (vr0 & 7)) * 8];
      bf16x8 vf2 = *(const bf16x8*)&Vb[vr1 * 64 + ((cb + 0) ^ (vr1 & 7)) * 8];
      bf16x8 vf3 = *(const bf16x8*)&Vb[vr1 * 64 + ((cb + 2) ^ (vr1 & 7)) * 8];
      __builtin_amdgcn_s_setprio(1);
      o0 = MFMA32(vf0, f0.v, o0);
      o0 = MFMA32(vf1, f1.v, o0);
      o1 = MFMA32(vf2, f0.v, o1);
      o1 = MFMA32(vf3, f1.v, o1);
      __builtin_amdgcn_s_setprio(0);
    }
    __syncthreads();
  }
  lsum += __shfl_xor(lsum, 32);
  float rl = 1.0f / lsum;
  int b = bh >> 3, h = bh & 7;
  unsigned short* aorow = ao + ((size_t)(b * 1024 + q0 + lq)) * 512 + h * 64;
  #pragma unroll
  for (int dt2 = 0; dt2 < 2; ++dt2) {
    #pragma unroll
    for (int g = 0; g < 4; ++g) {
      ushort4 pk;
      float v0 = (dt2 ? o1[4 * g + 0] : o0[4 * g + 0]) * rl;
      float v1 = (dt2 ? o1[4 * g + 1] : o0[4 * g + 1]) * rl;
      float v2 = (dt2 ? o1[4 * g + 2] : o0[4 * g + 2]) * rl;
      float v3 = (dt2 ? o1[4 * g + 3] : o0[4 * g + 3]) * rl;
      pk.x = f2bf(v0); pk.y = f2bf(v1); pk.z = f2bf(v2); pk.w = f2bf(v3);
      *(ushort4*)(aorow + dt2 * 32 + 8 * g + 4 * half) = pk;
    }
  }
}

// ---- kernel 6: output GEMM + bias, 4-wave blocks (128x64 tile) ------------
__global__ __launch_bounds__(256, 4) void k_out(const unsigned short* __restrict__ ao,
                                                const unsigned short* __restrict__ wot,
                                                const float* __restrict__ b_out,
                                                float* __restrict__ out) {
  __shared__ unsigned short As[3][128 * 32];
  __shared__ unsigned short Bs[3][64 * 32];
  int tid = threadIdx.x;
  int wid = tid >> 6, lane = tid & 63;
  int bm = blockIdx.x & 63, bn = blockIdx.x >> 6;   // 64 x 8
  int r0 = bm * 128, c0 = bn * 64;
  int lr = lane & 15, lk = (lane >> 4) * 8;
  int wr = (wid >> 1) * 64, wc = (wid & 1) * 32;    // 2M x 2N
  int srowA0 = tid >> 2, srowA1 = 64 + (tid >> 2), scol = (tid & 3) * 8;
  const unsigned short* gA0 = ao  + (size_t)(r0 + srowA0) * 512 + scol;
  const unsigned short* gA1 = ao  + (size_t)(r0 + srowA1) * 512 + scol;
  const unsigned short* gB  = wot + (size_t)(c0 + srowA0) * 512 + scol;  // rows 0..63
  int offA0 = tid * 8, offA1 = 2048 + tid * 8, offB = tid * 8;

  f32x4 acc[4][2];
  #pragma unroll
  for (int mi = 0; mi < 4; ++mi)
    #pragma unroll
    for (int ni = 0; ni < 2; ++ni)
      acc[mi][ni] = (f32x4){0.f, 0.f, 0.f, 0.f};

  GLD16(gA0,      &As[0][offA0]);
  GLD16(gA1,      &As[0][offA1]);
  GLD16(gB,       &Bs[0][offB]);
  GLD16(gA0 + 32, &As[1][offA0]);
  GLD16(gA1 + 32, &As[1][offA1]);
  GLD16(gB  + 32, &Bs[1][offB]);

  int cur = 0, pre = 2;
  for (int t = 0; t < 16; ++t) {
    if (t < 15) asm volatile("s_waitcnt vmcnt(3)" ::: "memory");
    else        asm volatile("s_waitcnt vmcnt(0)" ::: "memory");
    __builtin_amdgcn_s_barrier();
    if (t < 14) {
      int k2 = (t + 2) * 32;
      GLD16(gA0 + k2, &As[pre][offA0]);
      GLD16(gA1 + k2, &As[pre][offA1]);
      GLD16(gB  + k2, &Bs[pre][offB]);
    }
    bf16x8 af[4], bfr[2];
    #pragma unroll
    for (int mi = 0; mi < 4; ++mi)
      af[mi] = *(const bf16x8*)&As[cur][(wr + mi * 16 + lr) * 32 + lk];
    #pragma unroll
    for (int ni = 0; ni < 2; ++ni)
      bfr[ni] = *(const bf16x8*)&Bs[cur][(wc + ni * 16 + lr) * 32 + lk];
    __builtin_amdgcn_s_setprio(1);
    #pragma unroll
    for (int mi = 0; mi < 4; ++mi)
      #pragma unroll
      for (int ni = 0; ni < 2; ++ni)
        acc[mi][ni] = MFMA16(af[mi], bfr[ni], acc[mi][ni]);
    __builtin_amdgcn_s_setprio(0);
    cur = (cur == 2) ? 0 : cur + 1;
    pre = (pre == 2) ? 0 : pre + 1;
  }

  #pragma unroll
  for (int ni = 0; ni < 2; ++ni) {
    int col = c0 + wc + ni * 16 + lr;
    float bias = b_out[col];
    #pragma unroll
    for (int mi = 0; mi < 4; ++mi)
      #pragma unroll
      for (int reg = 0; reg < 4; ++reg) {
        int row = r0 + wr + mi * 16 + (lane >> 4) * 4 + reg;
        out[(size_t)row * 512 + col] = acc[mi][ni][reg] + bias;
      }
  }
}

// ---------------------------------------------------------------------------
extern "C" void kernel_launch(void* const* d_in, const int* in_sizes, int n_in,
                              void* d_out, int out_size, void* d_ws, size_t ws_size,
                              hipStream_t stream) {
  const float* img       = (const float*)d_in[0];
  const float* tab       = (const float*)d_in[1];
  const float* w_qkv     = (const float*)d_in[2];
  const float* w_tab_qkv = (const float*)d_in[3];
  const float* w_out     = (const float*)d_in[4];
  const float* b_out     = (const float*)d_in[5];
  const float* ln_w      = (const float*)d_in[6];
  const float* ln_b      = (const float*)d_in[7];
  char* ws = (char*)d_ws;
  unsigned short* x_bf = (unsigned short*)(ws);             //  8 MiB
  unsigned short* wqt  = (unsigned short*)(ws + 8388608);   //  1.5 MiB
  unsigned short* wot  = (unsigned short*)(ws + 9961472);   //  0.5 MiB
  unsigned short* qh   = (unsigned short*)(ws + 10485760);  //  8 MiB
  unsigned short* kh   = (unsigned short*)(ws + 18874368);  //  8.5 MiB (KPAD)
  unsigned short* vt   = (unsigned short*)(ws + 27787264);  //  8.5 MiB (KPAD)
  unsigned short* ao   = (unsigned short*)(ws + 36700160);  //  8 MiB
  float* out = (float*)d_out;

  hipLaunchKernelGGL(k_pre,  dim3(2432), dim3(256), 0, stream,
                     img, tab, w_qkv, w_tab_qkv, w_out, ln_w, ln_b,
                     x_bf, wqt, wot, kh, vt);
  hipLaunchKernelGGL(k_qkv,  dim3(768),  dim3(512), 0, stream, x_bf, wqt, qh, kh, vt);
  hipLaunchKernelGGL(k_attn, dim3(256),  dim3(512), 0, stream, qh, kh, vt, ao);
  hipLaunchKernelGGL(k_out,  dim3(512),  dim3(256), 0, stream, ao, wot, b_out, out);
}